// Round 1
// baseline (385.337 us; speedup 1.0000x reference)
//
#include <hip/hip_runtime.h>
#include <hip/hip_bf16.h>

typedef __bf16 bf16_t;
typedef __bf16 bf16x8 __attribute__((ext_vector_type(8)));
typedef __bf16 bf16x4 __attribute__((ext_vector_type(4)));
typedef float f32x4 __attribute__((ext_vector_type(4)));

#define S_LEN 2048
#define HID   2048
#define NH    16
#define HD    128
#define QKVN  2304   // 2048 + 2*128
#define NEG_BIG (-30000.0f)
#define RESCALE_THR 8.0f

// direct global->LDS DMA, 16B per lane. lds dst must be the WAVE-UNIFORM base;
// HW adds lane*16 itself (m104). No LDS padding allowed in the covered range.
__device__ __forceinline__ void gld_lds16(const bf16_t* g, bf16_t* l) {
  __builtin_amdgcn_global_load_lds(
      (const __attribute__((address_space(1))) void*)((const void*)g),
      (__attribute__((address_space(3))) void*)((void*)l), 16, 0, 0);
}

// ---------------------------------------------------------------------------
// fp32 -> bf16 downcast, float4-vectorized.
// ---------------------------------------------------------------------------
__global__ __launch_bounds__(256) void cvt_f32_bf16_kernel(
    const float* __restrict__ in, bf16_t* __restrict__ out, int n)
{
  int i = (blockIdx.x * 256 + threadIdx.x) * 4;
  if (i < n) {
    float4 v = *(const float4*)(in + i);
    bf16x4 o;
    o[0] = (bf16_t)v.x; o[1] = (bf16_t)v.y; o[2] = (bf16_t)v.z; o[3] = (bf16_t)v.w;
    *(bf16x4*)(out + i) = o;
  }
}

// ---------------------------------------------------------------------------
// fp32 W[K][N] -> bf16 WT[N][K].
// ---------------------------------------------------------------------------
__global__ __launch_bounds__(256) void transpose_cvt_kernel(
    const float* __restrict__ in, bf16_t* __restrict__ out, int K, int N)
{
  int nc = threadIdx.x & 63;
  int kg = threadIdx.x >> 6;
  int n  = blockIdx.x * 64 + nc;
  int kb = blockIdx.y * 32 + kg * 8;
  bf16x8 v;
  #pragma unroll
  for (int i = 0; i < 8; ++i) v[i] = (bf16_t)in[(size_t)(kb + i) * N + n];
  *(bf16x8*)(out + (size_t)n * K + kb) = v;
}

// ---------------------------------------------------------------------------
// Extract V^T from qkv: vtg[b][d][s] = qkv[b*S+s][2176+d].
// ---------------------------------------------------------------------------
__global__ __launch_bounds__(256) void vt_extract_kernel(
    const bf16_t* __restrict__ qkv, bf16_t* __restrict__ vtg)
{
  int d  = threadIdx.x & 127;
  int sg = threadIdx.x >> 7;
  int b  = blockIdx.y;
  int s8 = blockIdx.x * 2 + sg;
  bf16x8 v;
  #pragma unroll
  for (int i = 0; i < 8; ++i)
    v[i] = qkv[((size_t)(b * S_LEN + s8 * 8 + i)) * QKVN + HID + HD + d];
  *(bf16x8*)(vtg + ((size_t)(b * HD + d)) * S_LEN + s8 * 8) = v;
}

// ---------------------------------------------------------------------------
// GEMM: C[M,N] = A[M,K] @ WT^T + bias (WT pre-transposed [N][K]).
// 128x128 C-tile, BK=64, 4 waves as 2x2 (wave owns 64x64, acc[4][4]).
// (unchanged this round)
// ---------------------------------------------------------------------------
template <typename OutT>
__global__ __launch_bounds__(256) void gemm_bias_kernel(
    const bf16_t* __restrict__ A, const bf16_t* __restrict__ WT,
    const float* __restrict__ bias, OutT* __restrict__ C,
    int K, int lda, int ldc)
{
  __shared__ bf16_t Ash[128 * 64];   // [m][k] swizzled, NO padding (lds-dma)
  __shared__ bf16_t Bsh[128 * 64];   // [n][k] swizzled, NO padding

  const int tid  = threadIdx.x;
  const int wave = tid >> 6;
  const int lane = tid & 63;
  const int quad = lane >> 4;
  const int c16  = lane & 15;
  const int wm = wave >> 1;          // 0..1 : row half
  const int wn = wave & 1;           // 0..1 : col half
  const int n0 = blockIdx.x * 128;
  const int m0 = blockIdx.y * 128;

  f32x4 acc[4][4] = {};

  for (int k0 = 0; k0 < K; k0 += 64) {
    __syncthreads();
    // 1024 16B-chunks per operand tile; wave stages [wave*256, wave*256+256)
    #pragma unroll
    for (int j = 0; j < 4; ++j) {
      int cbase = wave * 256 + j * 64;        // wave-uniform LDS base
      int c = cbase + lane;
      int row = c >> 3;
      int kcl = (c ^ row) & 7;                // xor-permuted chunk fetch
      gld_lds16(A  + (size_t)(m0 + row) * lda + k0 + kcl * 8, Ash + cbase * 8);
      gld_lds16(WT + (size_t)(n0 + row) * K   + k0 + kcl * 8, Bsh + cbase * 8);
    }
    __syncthreads();

    #pragma unroll
    for (int kk = 0; kk < 2; ++kk) {
      bf16x8 af[4], bfr[4];
      #pragma unroll
      for (int rb = 0; rb < 4; ++rb) {
        int row = wm * 64 + rb * 16 + c16;
        int kcp = ((kk * 4 + quad) ^ row) & 7;
        af[rb] = *(const bf16x8*)(Ash + row * 64 + kcp * 8);
      }
      #pragma unroll
      for (int nt = 0; nt < 4; ++nt) {
        int row = wn * 64 + nt * 16 + c16;
        int kcp = ((kk * 4 + quad) ^ row) & 7;
        bfr[nt] = *(const bf16x8*)(Bsh + row * 64 + kcp * 8);
      }
      #pragma unroll
      for (int rb = 0; rb < 4; ++rb)
        #pragma unroll
        for (int nt = 0; nt < 4; ++nt)
          acc[rb][nt] = __builtin_amdgcn_mfma_f32_16x16x32_bf16(af[rb], bfr[nt],
                                                                acc[rb][nt], 0, 0, 0);
    }
  }

  #pragma unroll
  for (int nt = 0; nt < 4; ++nt) {
    int col = n0 + wn * 64 + nt * 16 + c16;
    float bv = bias[col];
    #pragma unroll
    for (int rb = 0; rb < 4; ++rb) {
      int rbase = m0 + wm * 64 + rb * 16 + quad * 4;
      #pragma unroll
      for (int r = 0; r < 4; ++r)
        C[(size_t)(rbase + r) * ldc + col] = (OutT)(acc[rb][nt][r] + bv);
    }
  }
}

// ---------------------------------------------------------------------------
// Causal MQA attention, S^T formulation, 8 waves / 512 threads.
//
// Round-update vs previous version (was: MfmaUtil 14.4%, VALUBusy 37%,
// ~50% dead time, 101.5 us):
//  - T14 async-STAGE: next K/V tile is global-loaded into registers
//    (kpre/vpre, +32 VGPR) right after the current tile's LDS writes; the
//    loads stay in flight across QK^T + softmax + PV + 2 barriers. Only the
//    ds_writes remain between the barriers, removing ~global-load latency
//    from the per-tile critical path.
//  - T13 defer-max (THR=8, log2 domain): skip m-update + l*=alpha + the
//    32-mult O rescale when the tile max doesn't exceed m_q+8. P is then
//    bounded by 2^8=256 (bf16-safe); per-group (m,l,O) stay internally
//    consistent so the parity merge is unchanged.
// ---------------------------------------------------------------------------
__global__ __launch_bounds__(512, 4) void mqa_attn_kernel(
    const bf16_t* __restrict__ qkv, const bf16_t* __restrict__ vtg,
    bf16_t* __restrict__ out)
{
  __shared__ bf16_t Ksh[2][64 * 136];   // per-group K tile / P scratch / O scratch
  __shared__ bf16_t VTsh[2][128 * 72];  // per-group V^T tile / f32 combine scratch

  const int tid  = threadIdx.x;
  const int wave = tid >> 6;
  const int g    = wave >> 2;        // key-parity group
  const int wv   = wave & 3;         // q-strip within tile
  const int lane = tid & 63;
  const int quad = lane >> 4;
  const int c16  = lane & 15;
  const int gt   = tid & 255;        // thread id within group
  const int h = blockIdx.y;
  const int b = blockIdx.z;
  const float qscale = 0.08838834764831845f * 1.4426950408889634f; // /sqrt(128)*log2e

  const bf16_t* kbase = qkv + (size_t)b * S_LEN * QKVN + HID;
  const bf16_t* vtb   = vtg + (size_t)b * HD * S_LEN;

  // per-thread staging decomposition (constant across tiles)
  int kkey[4], kdcB[4], vdd[4], vkcB[4];
  #pragma unroll
  for (int i = 0; i < 4; ++i) {
    int c = gt + i * 256;
    kkey[i] = c >> 4;  kdcB[i] = (c & 15) * 8;
    vdd[i]  = c >> 3;  vkcB[i] = (c & 7) * 8;
  }

  for (int half = 0; half < 2; ++half) {
    const int qb = half ? (31 - (int)blockIdx.x) : (int)blockIdx.x;
    const int q0 = qb * 64;
    const int qrow = q0 + wv * 16 + c16;

    const bf16_t* qp = qkv + ((size_t)(b * S_LEN + qrow)) * QKVN + h * HD;
    bf16x8 qf[4];
    #pragma unroll
    for (int ks = 0; ks < 4; ++ks) {
      bf16x8 t = *(const bf16x8*)(qp + ks * 32 + quad * 8);
      #pragma unroll
      for (int j = 0; j < 8; ++j) t[j] = (bf16_t)((float)t[j] * qscale);
      qf[ks] = t;
    }

    float m_q = NEG_BIG, l_q = 0.0f;
    f32x4 o[8] = {};
    const int nss = (qb + 2) >> 1;

    // prologue prefetch: tile ss=0 (kt=g) into registers
    bf16x8 kpre[4], vpre[4];
    if (g <= qb) {
      int kb = g * 64;
      #pragma unroll
      for (int i = 0; i < 4; ++i) {
        kpre[i] = *(const bf16x8*)(kbase + (size_t)(kb + kkey[i]) * QKVN + kdcB[i]);
        vpre[i] = *(const bf16x8*)(vtb + (size_t)vdd[i] * S_LEN + kb + vkcB[i]);
      }
    }

    for (int ss = 0; ss < nss; ++ss) {
      const int kt = 2 * ss + g;
      const bool active = (kt <= qb);

      __syncthreads();   // prior iteration's LDS reads (P + PV) complete
      if (active) {
        #pragma unroll
        for (int i = 0; i < 4; ++i) {
          *(bf16x8*)(&Ksh[g][kkey[i] * 136 + kdcB[i]])  = kpre[i];
          *(bf16x8*)(&VTsh[g][vdd[i] * 72 + vkcB[i]])   = vpre[i];
        }
      }
      // T14: issue next tile's global loads NOW; they fly across QK^T,
      // softmax, PV and two barriers before being consumed.
      {
        int ktn = kt + 2;
        if (ktn <= qb) {
          int kb = ktn * 64;
          #pragma unroll
          for (int i = 0; i < 4; ++i) {
            kpre[i] = *(const bf16x8*)(kbase + (size_t)(kb + kkey[i]) * QKVN + kdcB[i]);
            vpre[i] = *(const bf16x8*)(vtb + (size_t)vdd[i] * S_LEN + kb + vkcB[i]);
          }
        }
      }
      __syncthreads();

      float p[4][4];
      if (active) {
        f32x4 sacc[4] = {};
        #pragma unroll
        for (int mt = 0; mt < 4; ++mt) {
          #pragma unroll
          for (int ks = 0; ks < 4; ++ks) {
            bf16x8 kf = *(const bf16x8*)(&Ksh[g][(mt * 16 + c16) * 136 + ks * 32 + quad * 8]);
            sacc[mt] = __builtin_amdgcn_mfma_f32_16x16x32_bf16(kf, qf[ks], sacc[mt], 0, 0, 0);
          }
        }
        float mx = NEG_BIG;
        if (kt == qb) {
          #pragma unroll
          for (int mt = 0; mt < 4; ++mt) {
            #pragma unroll
            for (int r = 0; r < 4; ++r) {
              int key = kt * 64 + mt * 16 + quad * 4 + r;
              float v = sacc[mt][r];
              if (key > qrow) v = NEG_BIG;
              p[mt][r] = v;
              mx = fmaxf(mx, v);
            }
          }
        } else {
          #pragma unroll
          for (int mt = 0; mt < 4; ++mt) {
            #pragma unroll
            for (int r = 0; r < 4; ++r) {
              p[mt][r] = sacc[mt][r];
              mx = fmaxf(mx, sacc[mt][r]);
            }
          }
        }
        mx = fmaxf(mx, __shfl_xor(mx, 16));
        mx = fmaxf(mx, __shfl_xor(mx, 32));

        // T13 defer-max: only rescale when the running max grew by >THR.
        if (__any(mx > m_q + RESCALE_THR)) {
          float mn = fmaxf(m_q, mx);
          float alpha = __builtin_exp2f(m_q - mn);
          m_q = mn;
          l_q *= alpha;
          #pragma unroll
          for (int mt8 = 0; mt8 < 8; ++mt8) {
            #pragma unroll
            for (int r = 0; r < 4; ++r) o[mt8][r] *= alpha;
          }
        }

        float rs = 0.f;
        #pragma unroll
        for (int mt = 0; mt < 4; ++mt) {
          #pragma unroll
          for (int r = 0; r < 4; ++r) {
            float pe = __builtin_exp2f(p[mt][r] - m_q);
            p[mt][r] = pe;
            rs += pe;
          }
        }
        rs += __shfl_xor(rs, 16);
        rs += __shfl_xor(rs, 32);
        l_q += rs;
      }

      __syncthreads();   // all K-tile reads done -> Ksh[g] reusable for P
      if (active) {
        bf16_t* Pw = &Ksh[g][(wv * 16) * 136];
        #pragma unroll
        for (int mt = 0; mt < 4; ++mt) {
          bf16x4 pk;
          #pragma unroll
          for (int r = 0; r < 4; ++r) pk[r] = (bf16_t)p[mt][r];
          *(bf16x4*)(Pw + c16 * 136 + mt * 16 + quad * 4) = pk;
        }
        bf16x8 pf[2];
        #pragma unroll
        for (int kh = 0; kh < 2; ++kh)
          pf[kh] = *(const bf16x8*)(Pw + c16 * 136 + kh * 32 + quad * 8);
        #pragma unroll
        for (int mt8 = 0; mt8 < 8; ++mt8) {
          #pragma unroll
          for (int kh = 0; kh < 2; ++kh) {
            bf16x8 vf = *(const bf16x8*)(&VTsh[g][(mt8 * 16 + c16) * 72 + kh * 32 + quad * 8]);
            o[mt8] = __builtin_amdgcn_mfma_f32_16x16x32_bf16(vf, pf[kh], o[mt8], 0, 0, 0);
          }
        }
      }
    }

    // ---- merge parity groups ----
    __syncthreads();
    float* scr = (float*)&VTsh[0][0];
    float* mls = scr + 4 * 16 * 132;
    if (g == 1) {
      float* op = scr + (wv * 16 + c16) * 132;
      #pragma unroll
      for (int mt8 = 0; mt8 < 8; ++mt8)
        *(f32x4*)(op + mt8 * 16 + quad * 4) = o[mt8];
      if (quad == 0) {
        mls[wv * 32 + c16] = m_q;
        mls[wv * 32 + 16 + c16] = l_q;
      }
    }
    __syncthreads();
    if (g == 0) {
      float m1 = mls[wv * 32 + c16];
      float l1 = mls[wv * 32 + 16 + c16];
      float mF = fmaxf(m_q, m1);
      float a0 = __builtin_exp2f(m_q - mF);
      float a1 = __builtin_exp2f(m1 - mF);
      float inv = 1.0f / fmaxf(a0 * l_q + a1 * l1, 1e-20f);
      a0 *= inv; a1 *= inv;
      const float* op = scr + (wv * 16 + c16) * 132;
      bf16_t* Osh = &Ksh[0][(wv * 16) * 136];
      #pragma unroll
      for (int mt8 = 0; mt8 < 8; ++mt8) {
        f32x4 o1 = *(const f32x4*)(op + mt8 * 16 + quad * 4);
        bf16x4 pk;
        #pragma unroll
        for (int r = 0; r < 4; ++r) pk[r] = (bf16_t)(o[mt8][r] * a0 + o1[r] * a1);
        *(bf16x4*)(Osh + c16 * 136 + mt8 * 16 + quad * 4) = pk;
      }
      int ql = lane >> 2, dc = lane & 3;
      #pragma unroll
      for (int i = 0; i < 4; ++i) {
        bf16x8 v = *(const bf16x8*)(Osh + ql * 136 + dc * 8 + i * 32);
        *(bf16x8*)(out + ((size_t)(b * S_LEN + q0 + wv * 16 + ql)) * HID
                       + h * HD + dc * 8 + i * 32) = v;
      }
    }
  }
}

extern "C" void kernel_launch(void* const* d_in, const int* in_sizes, int n_in,
                              void* d_out, int out_size, void* d_ws, size_t ws_size,
                              hipStream_t stream) {
  const float* hidden_f   = (const float*)d_in[0];
  // d_in[1] = attention_mask (deterministic causal) -- ignored
  const float* c_attn_w_f = (const float*)d_in[2];
  const float* c_attn_b_f = (const float*)d_in[3];
  const float* c_proj_w_f = (const float*)d_in[4];
  const float* c_proj_b_f = (const float*)d_in[5];
  float* out = (float*)d_out;

  const int M = 2 * S_LEN;                 // 4096
  const int nH  = M * HID;
  const int nWq = HID * QKVN;
  const int nWp = HID * HID;

  bf16_t* hbf   = (bf16_t*)d_ws;
  bf16_t* wqT   = hbf  + nH;               // WT_qkv [2304][2048]
  bf16_t* wpT   = wqT  + nWq;              // WT_proj[2048][2048]
  bf16_t* qkv   = wpT  + nWp;              // [4096][2304]
  bf16_t* attn  = qkv  + (size_t)M * QKVN; // [4096][2048]
  bf16_t* vtg   = attn + (size_t)M * HID;  // V^T [2][128][2048]

  cvt_f32_bf16_kernel<<<nH / 1024, 256, 0, stream>>>(hidden_f, hbf, nH);
  dim3 gt1(QKVN / 64, HID / 32);
  transpose_cvt_kernel<<<gt1, 256, 0, stream>>>(c_attn_w_f, wqT, HID, QKVN);
  dim3 gt2(HID / 64, HID / 32);
  transpose_cvt_kernel<<<gt2, 256, 0, stream>>>(c_proj_w_f, wpT, HID, HID);

  dim3 g1(QKVN / 128, M / 128);
  gemm_bias_kernel<bf16_t><<<g1, 256, 0, stream>>>(hbf, wqT, c_attn_b_f, qkv,
                                                   HID, HID, QKVN);

  dim3 gv(S_LEN / 16, 2);
  vt_extract_kernel<<<gv, 256, 0, stream>>>(qkv, vtg);

  dim3 g2(16, NH, 2);
  mqa_attn_kernel<<<g2, 512, 0, stream>>>(qkv, vtg, attn);

  dim3 g3(HID / 128, M / 128);
  gemm_bias_kernel<float><<<g3, 256, 0, stream>>>(attn, wpT, c_proj_b_f, out,
                                                  HID, HID, HID);
}

// Round 2
// 340.081 us; speedup vs baseline: 1.1331x; 1.1331x over previous
//
#include <hip/hip_runtime.h>
#include <hip/hip_bf16.h>

typedef __bf16 bf16_t;
typedef __bf16 bf16x8 __attribute__((ext_vector_type(8)));
typedef __bf16 bf16x4 __attribute__((ext_vector_type(4)));
typedef float f32x4 __attribute__((ext_vector_type(4)));

#define S_LEN 2048
#define HID   2048
#define NH    16
#define HD    128
#define QKVN  2304   // 2048 + 2*128
#define NEG_BIG (-30000.0f)
#define RESCALE_THR 8.0f

// direct global->LDS DMA, 16B per lane. lds dst must be the WAVE-UNIFORM base;
// HW adds lane*16 itself (m104). No LDS padding allowed in the covered range.
__device__ __forceinline__ void gld_lds16(const bf16_t* g, bf16_t* l) {
  __builtin_amdgcn_global_load_lds(
      (const __attribute__((address_space(1))) void*)((const void*)g),
      (__attribute__((address_space(3))) void*)((void*)l), 16, 0, 0);
}

// ---------------------------------------------------------------------------
// fp32 -> bf16 downcast, float4-vectorized.
// ---------------------------------------------------------------------------
__global__ __launch_bounds__(256) void cvt_f32_bf16_kernel(
    const float* __restrict__ in, bf16_t* __restrict__ out, int n)
{
  int i = (blockIdx.x * 256 + threadIdx.x) * 4;
  if (i < n) {
    float4 v = *(const float4*)(in + i);
    bf16x4 o;
    o[0] = (bf16_t)v.x; o[1] = (bf16_t)v.y; o[2] = (bf16_t)v.z; o[3] = (bf16_t)v.w;
    *(bf16x4*)(out + i) = o;
  }
}

// ---------------------------------------------------------------------------
// fp32 W[K][N] -> bf16 WT[N][K].
// ---------------------------------------------------------------------------
__global__ __launch_bounds__(256) void transpose_cvt_kernel(
    const float* __restrict__ in, bf16_t* __restrict__ out, int K, int N)
{
  int nc = threadIdx.x & 63;
  int kg = threadIdx.x >> 6;
  int n  = blockIdx.x * 64 + nc;
  int kb = blockIdx.y * 32 + kg * 8;
  bf16x8 v;
  #pragma unroll
  for (int i = 0; i < 8; ++i) v[i] = (bf16_t)in[(size_t)(kb + i) * N + n];
  *(bf16x8*)(out + (size_t)n * K + kb) = v;
}

// ---------------------------------------------------------------------------
// Extract V^T from qkv: vtg[b][d][s] = qkv[b*S+s][2176+d].
// ---------------------------------------------------------------------------
__global__ __launch_bounds__(256) void vt_extract_kernel(
    const bf16_t* __restrict__ qkv, bf16_t* __restrict__ vtg)
{
  int d  = threadIdx.x & 127;
  int sg = threadIdx.x >> 7;
  int b  = blockIdx.y;
  int s8 = blockIdx.x * 2 + sg;
  bf16x8 v;
  #pragma unroll
  for (int i = 0; i < 8; ++i)
    v[i] = qkv[((size_t)(b * S_LEN + s8 * 8 + i)) * QKVN + HID + HD + d];
  *(bf16x8*)(vtg + ((size_t)(b * HD + d)) * S_LEN + s8 * 8) = v;
}

// ---------------------------------------------------------------------------
// GEMM: C[M,N] = A[M,K] @ WT^T + bias (WT pre-transposed [N][K]).
// 128x128 C-tile, BK=64, 4 waves as 2x2 (wave owns 64x64, acc[4][4]).
// (unchanged)
// ---------------------------------------------------------------------------
template <typename OutT>
__global__ __launch_bounds__(256) void gemm_bias_kernel(
    const bf16_t* __restrict__ A, const bf16_t* __restrict__ WT,
    const float* __restrict__ bias, OutT* __restrict__ C,
    int K, int lda, int ldc)
{
  __shared__ bf16_t Ash[128 * 64];   // [m][k] swizzled, NO padding (lds-dma)
  __shared__ bf16_t Bsh[128 * 64];   // [n][k] swizzled, NO padding

  const int tid  = threadIdx.x;
  const int wave = tid >> 6;
  const int lane = tid & 63;
  const int quad = lane >> 4;
  const int c16  = lane & 15;
  const int wm = wave >> 1;          // 0..1 : row half
  const int wn = wave & 1;           // 0..1 : col half
  const int n0 = blockIdx.x * 128;
  const int m0 = blockIdx.y * 128;

  f32x4 acc[4][4] = {};

  for (int k0 = 0; k0 < K; k0 += 64) {
    __syncthreads();
    // 1024 16B-chunks per operand tile; wave stages [wave*256, wave*256+256)
    #pragma unroll
    for (int j = 0; j < 4; ++j) {
      int cbase = wave * 256 + j * 64;        // wave-uniform LDS base
      int c = cbase + lane;
      int row = c >> 3;
      int kcl = (c ^ row) & 7;                // xor-permuted chunk fetch
      gld_lds16(A  + (size_t)(m0 + row) * lda + k0 + kcl * 8, Ash + cbase * 8);
      gld_lds16(WT + (size_t)(n0 + row) * K   + k0 + kcl * 8, Bsh + cbase * 8);
    }
    __syncthreads();

    #pragma unroll
    for (int kk = 0; kk < 2; ++kk) {
      bf16x8 af[4], bfr[4];
      #pragma unroll
      for (int rb = 0; rb < 4; ++rb) {
        int row = wm * 64 + rb * 16 + c16;
        int kcp = ((kk * 4 + quad) ^ row) & 7;
        af[rb] = *(const bf16x8*)(Ash + row * 64 + kcp * 8);
      }
      #pragma unroll
      for (int nt = 0; nt < 4; ++nt) {
        int row = wn * 64 + nt * 16 + c16;
        int kcp = ((kk * 4 + quad) ^ row) & 7;
        bfr[nt] = *(const bf16x8*)(Bsh + row * 64 + kcp * 8);
      }
      #pragma unroll
      for (int rb = 0; rb < 4; ++rb)
        #pragma unroll
        for (int nt = 0; nt < 4; ++nt)
          acc[rb][nt] = __builtin_amdgcn_mfma_f32_16x16x32_bf16(af[rb], bfr[nt],
                                                                acc[rb][nt], 0, 0, 0);
    }
  }

  #pragma unroll
  for (int nt = 0; nt < 4; ++nt) {
    int col = n0 + wn * 64 + nt * 16 + c16;
    float bv = bias[col];
    #pragma unroll
    for (int rb = 0; rb < 4; ++rb) {
      int rbase = m0 + wm * 64 + rb * 16 + quad * 4;
      #pragma unroll
      for (int r = 0; r < 4; ++r)
        C[(size_t)(rbase + r) * ldc + col] = (OutT)(acc[rb][nt][r] + bv);
    }
  }
}

// ---------------------------------------------------------------------------
// Causal MQA attention, S^T formulation, 8 waves / 512 threads.
//
// Round-2 update (round-1 post-mortem: T14 reg-prefetch spilled to scratch —
// WRITE_SIZE 16->110 MB, dur 101->144 us; peak-live ~140 VGPR > 128 cap at
// launch_bounds(512,4). REVERTED. T13 verified correct in round 1 — kept):
//  - staging: round-0 direct global->LDS loop (fits 128-VGPR budget)
//  - T13 defer-max (THR=8, log2 domain): skip m-update + l*=alpha + the
//    32-mult O rescale when the tile max doesn't exceed m_q+8. P bounded by
//    2^8 (bf16-safe).
//  - T5 s_setprio(1) around both MFMA clusters: wave role-diversity exists
//    here (parity groups with divergent `active`, 2 independent blocks/CU)
//    — the regime where m191 measured +4-7% on attention.
// ---------------------------------------------------------------------------
__global__ __launch_bounds__(512, 4) void mqa_attn_kernel(
    const bf16_t* __restrict__ qkv, const bf16_t* __restrict__ vtg,
    bf16_t* __restrict__ out)
{
  __shared__ bf16_t Ksh[2][64 * 136];   // per-group K tile / P scratch / O scratch
  __shared__ bf16_t VTsh[2][128 * 72];  // per-group V^T tile / f32 combine scratch

  const int tid  = threadIdx.x;
  const int wave = tid >> 6;
  const int g    = wave >> 2;        // key-parity group
  const int wv   = wave & 3;         // q-strip within tile
  const int lane = tid & 63;
  const int quad = lane >> 4;
  const int c16  = lane & 15;
  const int gt   = tid & 255;        // thread id within group
  const int h = blockIdx.y;
  const int b = blockIdx.z;
  const float qscale = 0.08838834764831845f * 1.4426950408889634f; // /sqrt(128)*log2e

  const bf16_t* kbase = qkv + (size_t)b * S_LEN * QKVN + HID;
  const bf16_t* vtb   = vtg + (size_t)b * HD * S_LEN;

  for (int half = 0; half < 2; ++half) {
    const int qb = half ? (31 - (int)blockIdx.x) : (int)blockIdx.x;
    const int q0 = qb * 64;
    const int qrow = q0 + wv * 16 + c16;

    const bf16_t* qp = qkv + ((size_t)(b * S_LEN + qrow)) * QKVN + h * HD;
    bf16x8 qf[4];
    #pragma unroll
    for (int ks = 0; ks < 4; ++ks) {
      bf16x8 t = *(const bf16x8*)(qp + ks * 32 + quad * 8);
      #pragma unroll
      for (int j = 0; j < 8; ++j) t[j] = (bf16_t)((float)t[j] * qscale);
      qf[ks] = t;
    }

    float m_q = NEG_BIG, l_q = 0.0f;
    f32x4 o[8] = {};
    const int nss = (qb + 2) >> 1;

    for (int ss = 0; ss < nss; ++ss) {
      const int kt = 2 * ss + g;
      const bool active = (kt <= qb);

      __syncthreads();
      if (active) {
        for (int c = gt; c < 1024; c += 256) {
          int key = c >> 4, dc = c & 15;
          *(bf16x8*)(&Ksh[g][key * 136 + dc * 8]) =
              *(const bf16x8*)(kbase + (size_t)(kt * 64 + key) * QKVN + dc * 8);
        }
        for (int c = gt; c < 1024; c += 256) {
          int d = c >> 3, kc = c & 7;
          *(bf16x8*)(&VTsh[g][d * 72 + kc * 8]) =
              *(const bf16x8*)(vtb + (size_t)d * S_LEN + kt * 64 + kc * 8);
        }
      }
      __syncthreads();

      float p[4][4];
      if (active) {
        f32x4 sacc[4] = {};
        __builtin_amdgcn_s_setprio(1);
        #pragma unroll
        for (int mt = 0; mt < 4; ++mt) {
          #pragma unroll
          for (int ks = 0; ks < 4; ++ks) {
            bf16x8 kf = *(const bf16x8*)(&Ksh[g][(mt * 16 + c16) * 136 + ks * 32 + quad * 8]);
            sacc[mt] = __builtin_amdgcn_mfma_f32_16x16x32_bf16(kf, qf[ks], sacc[mt], 0, 0, 0);
          }
        }
        __builtin_amdgcn_s_setprio(0);
        float mx = NEG_BIG;
        if (kt == qb) {
          #pragma unroll
          for (int mt = 0; mt < 4; ++mt) {
            #pragma unroll
            for (int r = 0; r < 4; ++r) {
              int key = kt * 64 + mt * 16 + quad * 4 + r;
              float v = sacc[mt][r];
              if (key > qrow) v = NEG_BIG;
              p[mt][r] = v;
              mx = fmaxf(mx, v);
            }
          }
        } else {
          #pragma unroll
          for (int mt = 0; mt < 4; ++mt) {
            #pragma unroll
            for (int r = 0; r < 4; ++r) {
              p[mt][r] = sacc[mt][r];
              mx = fmaxf(mx, sacc[mt][r]);
            }
          }
        }
        mx = fmaxf(mx, __shfl_xor(mx, 16));
        mx = fmaxf(mx, __shfl_xor(mx, 32));

        // T13 defer-max: only rescale when the running max grew by >THR.
        if (__any(mx > m_q + RESCALE_THR)) {
          float mn = fmaxf(m_q, mx);
          float alpha = __builtin_exp2f(m_q - mn);
          m_q = mn;
          l_q *= alpha;
          #pragma unroll
          for (int mt8 = 0; mt8 < 8; ++mt8) {
            #pragma unroll
            for (int r = 0; r < 4; ++r) o[mt8][r] *= alpha;
          }
        }

        float rs = 0.f;
        #pragma unroll
        for (int mt = 0; mt < 4; ++mt) {
          #pragma unroll
          for (int r = 0; r < 4; ++r) {
            float pe = __builtin_exp2f(p[mt][r] - m_q);
            p[mt][r] = pe;
            rs += pe;
          }
        }
        rs += __shfl_xor(rs, 16);
        rs += __shfl_xor(rs, 32);
        l_q += rs;
      }

      __syncthreads();   // all K-tile reads done -> Ksh[g] reusable for P
      if (active) {
        bf16_t* Pw = &Ksh[g][(wv * 16) * 136];
        #pragma unroll
        for (int mt = 0; mt < 4; ++mt) {
          bf16x4 pk;
          #pragma unroll
          for (int r = 0; r < 4; ++r) pk[r] = (bf16_t)p[mt][r];
          *(bf16x4*)(Pw + c16 * 136 + mt * 16 + quad * 4) = pk;
        }
        bf16x8 pf[2];
        #pragma unroll
        for (int kh = 0; kh < 2; ++kh)
          pf[kh] = *(const bf16x8*)(Pw + c16 * 136 + kh * 32 + quad * 8);
        __builtin_amdgcn_s_setprio(1);
        #pragma unroll
        for (int mt8 = 0; mt8 < 8; ++mt8) {
          #pragma unroll
          for (int kh = 0; kh < 2; ++kh) {
            bf16x8 vf = *(const bf16x8*)(&VTsh[g][(mt8 * 16 + c16) * 72 + kh * 32 + quad * 8]);
            o[mt8] = __builtin_amdgcn_mfma_f32_16x16x32_bf16(vf, pf[kh], o[mt8], 0, 0, 0);
          }
        }
        __builtin_amdgcn_s_setprio(0);
      }
    }

    // ---- merge parity groups ----
    __syncthreads();
    float* scr = (float*)&VTsh[0][0];
    float* mls = scr + 4 * 16 * 132;
    if (g == 1) {
      float* op = scr + (wv * 16 + c16) * 132;
      #pragma unroll
      for (int mt8 = 0; mt8 < 8; ++mt8)
        *(f32x4*)(op + mt8 * 16 + quad * 4) = o[mt8];
      if (quad == 0) {
        mls[wv * 32 + c16] = m_q;
        mls[wv * 32 + 16 + c16] = l_q;
      }
    }
    __syncthreads();
    if (g == 0) {
      float m1 = mls[wv * 32 + c16];
      float l1 = mls[wv * 32 + 16 + c16];
      float mF = fmaxf(m_q, m1);
      float a0 = __builtin_exp2f(m_q - mF);
      float a1 = __builtin_exp2f(m1 - mF);
      float inv = 1.0f / fmaxf(a0 * l_q + a1 * l1, 1e-20f);
      a0 *= inv; a1 *= inv;
      const float* op = scr + (wv * 16 + c16) * 132;
      bf16_t* Osh = &Ksh[0][(wv * 16) * 136];
      #pragma unroll
      for (int mt8 = 0; mt8 < 8; ++mt8) {
        f32x4 o1 = *(const f32x4*)(op + mt8 * 16 + quad * 4);
        bf16x4 pk;
        #pragma unroll
        for (int r = 0; r < 4; ++r) pk[r] = (bf16_t)(o[mt8][r] * a0 + o1[r] * a1);
        *(bf16x4*)(Osh + c16 * 136 + mt8 * 16 + quad * 4) = pk;
      }
      int ql = lane >> 2, dc = lane & 3;
      #pragma unroll
      for (int i = 0; i < 4; ++i) {
        bf16x8 v = *(const bf16x8*)(Osh + ql * 136 + dc * 8 + i * 32);
        *(bf16x8*)(out + ((size_t)(b * S_LEN + q0 + wv * 16 + ql)) * HID
                       + h * HD + dc * 8 + i * 32) = v;
      }
    }
  }
}

extern "C" void kernel_launch(void* const* d_in, const int* in_sizes, int n_in,
                              void* d_out, int out_size, void* d_ws, size_t ws_size,
                              hipStream_t stream) {
  const float* hidden_f   = (const float*)d_in[0];
  // d_in[1] = attention_mask (deterministic causal) -- ignored
  const float* c_attn_w_f = (const float*)d_in[2];
  const float* c_attn_b_f = (const float*)d_in[3];
  const float* c_proj_w_f = (const float*)d_in[4];
  const float* c_proj_b_f = (const float*)d_in[5];
  float* out = (float*)d_out;

  const int M = 2 * S_LEN;                 // 4096
  const int nH  = M * HID;
  const int nWq = HID * QKVN;
  const int nWp = HID * HID;

  bf16_t* hbf   = (bf16_t*)d_ws;
  bf16_t* wqT   = hbf  + nH;               // WT_qkv [2304][2048]
  bf16_t* wpT   = wqT  + nWq;              // WT_proj[2048][2048]
  bf16_t* qkv   = wpT  + nWp;              // [4096][2304]
  bf16_t* attn  = qkv  + (size_t)M * QKVN; // [4096][2048]
  bf16_t* vtg   = attn + (size_t)M * HID;  // V^T [2][128][2048]

  cvt_f32_bf16_kernel<<<nH / 1024, 256, 0, stream>>>(hidden_f, hbf, nH);
  dim3 gt1(QKVN / 64, HID / 32);
  transpose_cvt_kernel<<<gt1, 256, 0, stream>>>(c_attn_w_f, wqT, HID, QKVN);
  dim3 gt2(HID / 64, HID / 32);
  transpose_cvt_kernel<<<gt2, 256, 0, stream>>>(c_proj_w_f, wpT, HID, HID);

  dim3 g1(QKVN / 128, M / 128);
  gemm_bias_kernel<bf16_t><<<g1, 256, 0, stream>>>(hbf, wqT, c_attn_b_f, qkv,
                                                   HID, HID, QKVN);

  dim3 gv(S_LEN / 16, 2);
  vt_extract_kernel<<<gv, 256, 0, stream>>>(qkv, vtg);

  dim3 g2(16, NH, 2);
  mqa_attn_kernel<<<g2, 512, 0, stream>>>(qkv, vtg, attn);

  dim3 g3(HID / 128, M / 128);
  gemm_bias_kernel<float><<<g3, 256, 0, stream>>>(attn, wpT, c_proj_b_f, out,
                                                  HID, HID, HID);
}

// Round 5
// 337.985 us; speedup vs baseline: 1.1401x; 1.0062x over previous
//
#include <hip/hip_runtime.h>
#include <hip/hip_bf16.h>

typedef __bf16 bf16_t;
typedef __bf16 bf16x8 __attribute__((ext_vector_type(8)));
typedef __bf16 bf16x4 __attribute__((ext_vector_type(4)));
typedef float f32x4 __attribute__((ext_vector_type(4)));

#define S_LEN 2048
#define HID   2048
#define NH    16
#define HD    128
#define QKVN  2304   // 2048 + 2*128
#define NEG_BIG (-30000.0f)
#define RESCALE_THR 8.0f

// direct global->LDS DMA, 16B per lane. lds dst must be the WAVE-UNIFORM base;
// HW adds lane*16 itself (m104). No LDS padding allowed in the covered range.
__device__ __forceinline__ void gld_lds16(const bf16_t* g, bf16_t* l) {
  __builtin_amdgcn_global_load_lds(
      (const __attribute__((address_space(1))) void*)((const void*)g),
      (__attribute__((address_space(3))) void*)((void*)l), 16, 0, 0);
}

// ---------------------------------------------------------------------------
// fp32 -> bf16 downcast, float4-vectorized.
// ---------------------------------------------------------------------------
__global__ __launch_bounds__(256) void cvt_f32_bf16_kernel(
    const float* __restrict__ in, bf16_t* __restrict__ out, int n)
{
  int i = (blockIdx.x * 256 + threadIdx.x) * 4;
  if (i < n) {
    float4 v = *(const float4*)(in + i);
    bf16x4 o;
    o[0] = (bf16_t)v.x; o[1] = (bf16_t)v.y; o[2] = (bf16_t)v.z; o[3] = (bf16_t)v.w;
    *(bf16x4*)(out + i) = o;
  }
}

// ---------------------------------------------------------------------------
// fp32 W[K][N] -> bf16 WT[N][K].
// ---------------------------------------------------------------------------
__global__ __launch_bounds__(256) void transpose_cvt_kernel(
    const float* __restrict__ in, bf16_t* __restrict__ out, int K, int N)
{
  int nc = threadIdx.x & 63;
  int kg = threadIdx.x >> 6;
  int n  = blockIdx.x * 64 + nc;
  int kb = blockIdx.y * 32 + kg * 8;
  bf16x8 v;
  #pragma unroll
  for (int i = 0; i < 8; ++i) v[i] = (bf16_t)in[(size_t)(kb + i) * N + n];
  *(bf16x8*)(out + (size_t)n * K + kb) = v;
}

// ---------------------------------------------------------------------------
// Extract V^T from qkv: vtg[b][d][s] = qkv[b*S+s][2176+d].
// ---------------------------------------------------------------------------
__global__ __launch_bounds__(256) void vt_extract_kernel(
    const bf16_t* __restrict__ qkv, bf16_t* __restrict__ vtg)
{
  int d  = threadIdx.x & 127;
  int sg = threadIdx.x >> 7;
  int b  = blockIdx.y;
  int s8 = blockIdx.x * 2 + sg;
  bf16x8 v;
  #pragma unroll
  for (int i = 0; i < 8; ++i)
    v[i] = qkv[((size_t)(b * S_LEN + s8 * 8 + i)) * QKVN + HID + HD + d];
  *(bf16x8*)(vtg + ((size_t)(b * HD + d)) * S_LEN + s8 * 8) = v;
}

// ---------------------------------------------------------------------------
// GEMM: C[M,N] = A[M,K] @ WT^T + bias (WT pre-transposed [N][K]).
// 128x128 C-tile, BK=64, 4 waves as 2x2 (wave owns 64x64, acc[4][4]).
// Round-5 addition: T1 XCD-aware block swizzle (m204). Consecutive linear
// block ids share the same A row-panel; chunking 1/8th of the grid per XCD
// keeps each 512KB A-panel L2-resident instead of re-fetched by all 8 XCDs.
// Both launches have nwg%8==0 (576, 512) so the simple bijective form holds;
// guarded fallback otherwise.
// ---------------------------------------------------------------------------
template <typename OutT>
__global__ __launch_bounds__(256) void gemm_bias_kernel(
    const bf16_t* __restrict__ A, const bf16_t* __restrict__ WT,
    const float* __restrict__ bias, OutT* __restrict__ C,
    int K, int lda, int ldc)
{
  __shared__ bf16_t Ash[128 * 64];   // [m][k] swizzled, NO padding (lds-dma)
  __shared__ bf16_t Bsh[128 * 64];   // [n][k] swizzled, NO padding

  const int tid  = threadIdx.x;
  const int wave = tid >> 6;
  const int lane = tid & 63;
  const int quad = lane >> 4;
  const int c16  = lane & 15;
  const int wm = wave >> 1;          // 0..1 : row half
  const int wn = wave & 1;           // 0..1 : col half

  // T1 XCD swizzle: id -> (id%8)*cpx + id/8, bijective when nwg%8==0.
  int id  = (int)(blockIdx.y * gridDim.x + blockIdx.x);
  int nwg = (int)(gridDim.x * gridDim.y);
  int swz = (nwg & 7) ? id : ((id & 7) * (nwg >> 3) + (id >> 3));
  const int n0 = (swz % (int)gridDim.x) * 128;
  const int m0 = (swz / (int)gridDim.x) * 128;

  f32x4 acc[4][4] = {};

  for (int k0 = 0; k0 < K; k0 += 64) {
    __syncthreads();
    // 1024 16B-chunks per operand tile; wave stages [wave*256, wave*256+256)
    #pragma unroll
    for (int j = 0; j < 4; ++j) {
      int cbase = wave * 256 + j * 64;        // wave-uniform LDS base
      int c = cbase + lane;
      int row = c >> 3;
      int kcl = (c ^ row) & 7;                // xor-permuted chunk fetch
      gld_lds16(A  + (size_t)(m0 + row) * lda + k0 + kcl * 8, Ash + cbase * 8);
      gld_lds16(WT + (size_t)(n0 + row) * K   + k0 + kcl * 8, Bsh + cbase * 8);
    }
    __syncthreads();

    #pragma unroll
    for (int kk = 0; kk < 2; ++kk) {
      bf16x8 af[4], bfr[4];
      #pragma unroll
      for (int rb = 0; rb < 4; ++rb) {
        int row = wm * 64 + rb * 16 + c16;
        int kcp = ((kk * 4 + quad) ^ row) & 7;
        af[rb] = *(const bf16x8*)(Ash + row * 64 + kcp * 8);
      }
      #pragma unroll
      for (int nt = 0; nt < 4; ++nt) {
        int row = wn * 64 + nt * 16 + c16;
        int kcp = ((kk * 4 + quad) ^ row) & 7;
        bfr[nt] = *(const bf16x8*)(Bsh + row * 64 + kcp * 8);
      }
      #pragma unroll
      for (int rb = 0; rb < 4; ++rb)
        #pragma unroll
        for (int nt = 0; nt < 4; ++nt)
          acc[rb][nt] = __builtin_amdgcn_mfma_f32_16x16x32_bf16(af[rb], bfr[nt],
                                                                acc[rb][nt], 0, 0, 0);
    }
  }

  #pragma unroll
  for (int nt = 0; nt < 4; ++nt) {
    int col = n0 + wn * 64 + nt * 16 + c16;
    float bv = bias[col];
    #pragma unroll
    for (int rb = 0; rb < 4; ++rb) {
      int rbase = m0 + wm * 64 + rb * 16 + quad * 4;
      #pragma unroll
      for (int r = 0; r < 4; ++r)
        C[(size_t)(rbase + r) * ldc + col] = (OutT)(acc[rb][nt][r] + bv);
    }
  }
}

// ---------------------------------------------------------------------------
// Causal MQA attention, S^T formulation, 8 waves / 512 threads.
// BYTE-IDENTICAL to the verified round-2 version (passed, attn 97 us):
// rounds 3/4's QBLK-128 restructure crashed the container twice and is
// parked until infra-vs-kernel is disambiguated by this round.
//  - T13 defer-max (THR=8) + T5 setprio: verified rounds 1-2.
// ---------------------------------------------------------------------------
__global__ __launch_bounds__(512, 4) void mqa_attn_kernel(
    const bf16_t* __restrict__ qkv, const bf16_t* __restrict__ vtg,
    bf16_t* __restrict__ out)
{
  __shared__ bf16_t Ksh[2][64 * 136];   // per-group K tile / P scratch / O scratch
  __shared__ bf16_t VTsh[2][128 * 72];  // per-group V^T tile / f32 combine scratch

  const int tid  = threadIdx.x;
  const int wave = tid >> 6;
  const int g    = wave >> 2;        // key-parity group
  const int wv   = wave & 3;         // q-strip within tile
  const int lane = tid & 63;
  const int quad = lane >> 4;
  const int c16  = lane & 15;
  const int gt   = tid & 255;        // thread id within group
  const int h = blockIdx.y;
  const int b = blockIdx.z;
  const float qscale = 0.08838834764831845f * 1.4426950408889634f; // /sqrt(128)*log2e

  const bf16_t* kbase = qkv + (size_t)b * S_LEN * QKVN + HID;
  const bf16_t* vtb   = vtg + (size_t)b * HD * S_LEN;

  for (int half = 0; half < 2; ++half) {
    const int qb = half ? (31 - (int)blockIdx.x) : (int)blockIdx.x;
    const int q0 = qb * 64;
    const int qrow = q0 + wv * 16 + c16;

    const bf16_t* qp = qkv + ((size_t)(b * S_LEN + qrow)) * QKVN + h * HD;
    bf16x8 qf[4];
    #pragma unroll
    for (int ks = 0; ks < 4; ++ks) {
      bf16x8 t = *(const bf16x8*)(qp + ks * 32 + quad * 8);
      #pragma unroll
      for (int j = 0; j < 8; ++j) t[j] = (bf16_t)((float)t[j] * qscale);
      qf[ks] = t;
    }

    float m_q = NEG_BIG, l_q = 0.0f;
    f32x4 o[8] = {};
    const int nss = (qb + 2) >> 1;

    for (int ss = 0; ss < nss; ++ss) {
      const int kt = 2 * ss + g;
      const bool active = (kt <= qb);

      __syncthreads();
      if (active) {
        for (int c = gt; c < 1024; c += 256) {
          int key = c >> 4, dc = c & 15;
          *(bf16x8*)(&Ksh[g][key * 136 + dc * 8]) =
              *(const bf16x8*)(kbase + (size_t)(kt * 64 + key) * QKVN + dc * 8);
        }
        for (int c = gt; c < 1024; c += 256) {
          int d = c >> 3, kc = c & 7;
          *(bf16x8*)(&VTsh[g][d * 72 + kc * 8]) =
              *(const bf16x8*)(vtb + (size_t)d * S_LEN + kt * 64 + kc * 8);
        }
      }
      __syncthreads();

      float p[4][4];
      if (active) {
        f32x4 sacc[4] = {};
        __builtin_amdgcn_s_setprio(1);
        #pragma unroll
        for (int mt = 0; mt < 4; ++mt) {
          #pragma unroll
          for (int ks = 0; ks < 4; ++ks) {
            bf16x8 kf = *(const bf16x8*)(&Ksh[g][(mt * 16 + c16) * 136 + ks * 32 + quad * 8]);
            sacc[mt] = __builtin_amdgcn_mfma_f32_16x16x32_bf16(kf, qf[ks], sacc[mt], 0, 0, 0);
          }
        }
        __builtin_amdgcn_s_setprio(0);
        float mx = NEG_BIG;
        if (kt == qb) {
          #pragma unroll
          for (int mt = 0; mt < 4; ++mt) {
            #pragma unroll
            for (int r = 0; r < 4; ++r) {
              int key = kt * 64 + mt * 16 + quad * 4 + r;
              float v = sacc[mt][r];
              if (key > qrow) v = NEG_BIG;
              p[mt][r] = v;
              mx = fmaxf(mx, v);
            }
          }
        } else {
          #pragma unroll
          for (int mt = 0; mt < 4; ++mt) {
            #pragma unroll
            for (int r = 0; r < 4; ++r) {
              p[mt][r] = sacc[mt][r];
              mx = fmaxf(mx, sacc[mt][r]);
            }
          }
        }
        mx = fmaxf(mx, __shfl_xor(mx, 16));
        mx = fmaxf(mx, __shfl_xor(mx, 32));

        // T13 defer-max: only rescale when the running max grew by >THR.
        if (__any(mx > m_q + RESCALE_THR)) {
          float mn = fmaxf(m_q, mx);
          float alpha = __builtin_exp2f(m_q - mn);
          m_q = mn;
          l_q *= alpha;
          #pragma unroll
          for (int mt8 = 0; mt8 < 8; ++mt8) {
            #pragma unroll
            for (int r = 0; r < 4; ++r) o[mt8][r] *= alpha;
          }
        }

        float rs = 0.f;
        #pragma unroll
        for (int mt = 0; mt < 4; ++mt) {
          #pragma unroll
          for (int r = 0; r < 4; ++r) {
            float pe = __builtin_exp2f(p[mt][r] - m_q);
            p[mt][r] = pe;
            rs += pe;
          }
        }
        rs += __shfl_xor(rs, 16);
        rs += __shfl_xor(rs, 32);
        l_q += rs;
      }

      __syncthreads();   // all K-tile reads done -> Ksh[g] reusable for P
      if (active) {
        bf16_t* Pw = &Ksh[g][(wv * 16) * 136];
        #pragma unroll
        for (int mt = 0; mt < 4; ++mt) {
          bf16x4 pk;
          #pragma unroll
          for (int r = 0; r < 4; ++r) pk[r] = (bf16_t)p[mt][r];
          *(bf16x4*)(Pw + c16 * 136 + mt * 16 + quad * 4) = pk;
        }
        bf16x8 pf[2];
        #pragma unroll
        for (int kh = 0; kh < 2; ++kh)
          pf[kh] = *(const bf16x8*)(Pw + c16 * 136 + kh * 32 + quad * 8);
        __builtin_amdgcn_s_setprio(1);
        #pragma unroll
        for (int mt8 = 0; mt8 < 8; ++mt8) {
          #pragma unroll
          for (int kh = 0; kh < 2; ++kh) {
            bf16x8 vf = *(const bf16x8*)(&VTsh[g][(mt8 * 16 + c16) * 72 + kh * 32 + quad * 8]);
            o[mt8] = __builtin_amdgcn_mfma_f32_16x16x32_bf16(vf, pf[kh], o[mt8], 0, 0, 0);
          }
        }
        __builtin_amdgcn_s_setprio(0);
      }
    }

    // ---- merge parity groups ----
    __syncthreads();
    float* scr = (float*)&VTsh[0][0];
    float* mls = scr + 4 * 16 * 132;
    if (g == 1) {
      float* op = scr + (wv * 16 + c16) * 132;
      #pragma unroll
      for (int mt8 = 0; mt8 < 8; ++mt8)
        *(f32x4*)(op + mt8 * 16 + quad * 4) = o[mt8];
      if (quad == 0) {
        mls[wv * 32 + c16] = m_q;
        mls[wv * 32 + 16 + c16] = l_q;
      }
    }
    __syncthreads();
    if (g == 0) {
      float m1 = mls[wv * 32 + c16];
      float l1 = mls[wv * 32 + 16 + c16];
      float mF = fmaxf(m_q, m1);
      float a0 = __builtin_exp2f(m_q - mF);
      float a1 = __builtin_exp2f(m1 - mF);
      float inv = 1.0f / fmaxf(a0 * l_q + a1 * l1, 1e-20f);
      a0 *= inv; a1 *= inv;
      const float* op = scr + (wv * 16 + c16) * 132;
      bf16_t* Osh = &Ksh[0][(wv * 16) * 136];
      #pragma unroll
      for (int mt8 = 0; mt8 < 8; ++mt8) {
        f32x4 o1 = *(const f32x4*)(op + mt8 * 16 + quad * 4);
        bf16x4 pk;
        #pragma unroll
        for (int r = 0; r < 4; ++r) pk[r] = (bf16_t)(o[mt8][r] * a0 + o1[r] * a1);
        *(bf16x4*)(Osh + c16 * 136 + mt8 * 16 + quad * 4) = pk;
      }
      int ql = lane >> 2, dc = lane & 3;
      #pragma unroll
      for (int i = 0; i < 4; ++i) {
        bf16x8 v = *(const bf16x8*)(Osh + ql * 136 + dc * 8 + i * 32);
        *(bf16x8*)(out + ((size_t)(b * S_LEN + q0 + wv * 16 + ql)) * HID
                       + h * HD + dc * 8 + i * 32) = v;
      }
    }
  }
}

extern "C" void kernel_launch(void* const* d_in, const int* in_sizes, int n_in,
                              void* d_out, int out_size, void* d_ws, size_t ws_size,
                              hipStream_t stream) {
  const float* hidden_f   = (const float*)d_in[0];
  // d_in[1] = attention_mask (deterministic causal) -- ignored
  const float* c_attn_w_f = (const float*)d_in[2];
  const float* c_attn_b_f = (const float*)d_in[3];
  const float* c_proj_w_f = (const float*)d_in[4];
  const float* c_proj_b_f = (const float*)d_in[5];
  float* out = (float*)d_out;

  const int M = 2 * S_LEN;                 // 4096
  const int nH  = M * HID;
  const int nWq = HID * QKVN;
  const int nWp = HID * HID;

  bf16_t* hbf   = (bf16_t*)d_ws;
  bf16_t* wqT   = hbf  + nH;               // WT_qkv [2304][2048]
  bf16_t* wpT   = wqT  + nWq;              // WT_proj[2048][2048]
  bf16_t* qkv   = wpT  + nWp;              // [4096][2304]
  bf16_t* attn  = qkv  + (size_t)M * QKVN; // [4096][2048]
  bf16_t* vtg   = attn + (size_t)M * HID;  // V^T [2][128][2048]

  cvt_f32_bf16_kernel<<<nH / 1024, 256, 0, stream>>>(hidden_f, hbf, nH);
  dim3 gt1(QKVN / 64, HID / 32);
  transpose_cvt_kernel<<<gt1, 256, 0, stream>>>(c_attn_w_f, wqT, HID, QKVN);
  dim3 gt2(HID / 64, HID / 32);
  transpose_cvt_kernel<<<gt2, 256, 0, stream>>>(c_proj_w_f, wpT, HID, HID);

  dim3 g1(QKVN / 128, M / 128);
  gemm_bias_kernel<bf16_t><<<g1, 256, 0, stream>>>(hbf, wqT, c_attn_b_f, qkv,
                                                   HID, HID, QKVN);

  dim3 gv(S_LEN / 16, 2);
  vt_extract_kernel<<<gv, 256, 0, stream>>>(qkv, vtg);

  dim3 g2(16, NH, 2);
  mqa_attn_kernel<<<g2, 512, 0, stream>>>(qkv, vtg, attn);

  dim3 g3(HID / 128, M / 128);
  gemm_bias_kernel<float><<<g3, 256, 0, stream>>>(attn, wpT, c_proj_b_f, out,
                                                  HID, HID, HID);
}

// Round 6
// 333.627 us; speedup vs baseline: 1.1550x; 1.0131x over previous
//
#include <hip/hip_runtime.h>
#include <hip/hip_bf16.h>

typedef __bf16 bf16_t;
typedef __bf16 bf16x8 __attribute__((ext_vector_type(8)));
typedef __bf16 bf16x4 __attribute__((ext_vector_type(4)));
typedef float f32x4 __attribute__((ext_vector_type(4)));

#define S_LEN 2048
#define HID   2048
#define NH    16
#define HD    128
#define QKVN  2304   // 2048 + 2*128
#define NEG_BIG (-30000.0f)
#define RESCALE_THR 8.0f

// direct global->LDS DMA, 16B per lane. lds dst must be the WAVE-UNIFORM base;
// HW adds lane*16 itself (m104). No LDS padding allowed in the covered range.
__device__ __forceinline__ void gld_lds16(const bf16_t* g, bf16_t* l) {
  __builtin_amdgcn_global_load_lds(
      (const __attribute__((address_space(1))) void*)((const void*)g),
      (__attribute__((address_space(3))) void*)((void*)l), 16, 0, 0);
}

// ---------------------------------------------------------------------------
// fp32 -> bf16 downcast, float4-vectorized.
// ---------------------------------------------------------------------------
__global__ __launch_bounds__(256) void cvt_f32_bf16_kernel(
    const float* __restrict__ in, bf16_t* __restrict__ out, int n)
{
  int i = (blockIdx.x * 256 + threadIdx.x) * 4;
  if (i < n) {
    float4 v = *(const float4*)(in + i);
    bf16x4 o;
    o[0] = (bf16_t)v.x; o[1] = (bf16_t)v.y; o[2] = (bf16_t)v.z; o[3] = (bf16_t)v.w;
    *(bf16x4*)(out + i) = o;
  }
}

// ---------------------------------------------------------------------------
// fp32 W[K][N] -> bf16 WT[N][K].
// ---------------------------------------------------------------------------
__global__ __launch_bounds__(256) void transpose_cvt_kernel(
    const float* __restrict__ in, bf16_t* __restrict__ out, int K, int N)
{
  int nc = threadIdx.x & 63;
  int kg = threadIdx.x >> 6;
  int n  = blockIdx.x * 64 + nc;
  int kb = blockIdx.y * 32 + kg * 8;
  bf16x8 v;
  #pragma unroll
  for (int i = 0; i < 8; ++i) v[i] = (bf16_t)in[(size_t)(kb + i) * N + n];
  *(bf16x8*)(out + (size_t)n * K + kb) = v;
}

// ---------------------------------------------------------------------------
// Extract V^T from qkv: vtg[b][d][s] = qkv[b*S+s][2176+d].
// ---------------------------------------------------------------------------
__global__ __launch_bounds__(256) void vt_extract_kernel(
    const bf16_t* __restrict__ qkv, bf16_t* __restrict__ vtg)
{
  int d  = threadIdx.x & 127;
  int sg = threadIdx.x >> 7;
  int b  = blockIdx.y;
  int s8 = blockIdx.x * 2 + sg;
  bf16x8 v;
  #pragma unroll
  for (int i = 0; i < 8; ++i)
    v[i] = qkv[((size_t)(b * S_LEN + s8 * 8 + i)) * QKVN + HID + HD + d];
  *(bf16x8*)(vtg + ((size_t)(b * HD + d)) * S_LEN + s8 * 8) = v;
}

// ---------------------------------------------------------------------------
// GEMM: C[M,N] = A[M,K] @ WT^T + bias (WT pre-transposed [N][K]).
// 128x128 C-tile, BK=64, 4 waves as 2x2 (wave owns 64x64, acc[4][4]).
// T1 XCD-aware block swizzle (verified round 5): chunking 1/8th of the grid
// per XCD keeps each A row-panel L2-resident. Both launches nwg%8==0;
// guarded fallback otherwise.
// ---------------------------------------------------------------------------
template <typename OutT>
__global__ __launch_bounds__(256) void gemm_bias_kernel(
    const bf16_t* __restrict__ A, const bf16_t* __restrict__ WT,
    const float* __restrict__ bias, OutT* __restrict__ C,
    int K, int lda, int ldc)
{
  __shared__ bf16_t Ash[128 * 64];   // [m][k] swizzled, NO padding (lds-dma)
  __shared__ bf16_t Bsh[128 * 64];   // [n][k] swizzled, NO padding

  const int tid  = threadIdx.x;
  const int wave = tid >> 6;
  const int lane = tid & 63;
  const int quad = lane >> 4;
  const int c16  = lane & 15;
  const int wm = wave >> 1;          // 0..1 : row half
  const int wn = wave & 1;           // 0..1 : col half

  // T1 XCD swizzle: id -> (id%8)*cpx + id/8, bijective when nwg%8==0.
  int id  = (int)(blockIdx.y * gridDim.x + blockIdx.x);
  int nwg = (int)(gridDim.x * gridDim.y);
  int swz = (nwg & 7) ? id : ((id & 7) * (nwg >> 3) + (id >> 3));
  const int n0 = (swz % (int)gridDim.x) * 128;
  const int m0 = (swz / (int)gridDim.x) * 128;

  f32x4 acc[4][4] = {};

  for (int k0 = 0; k0 < K; k0 += 64) {
    __syncthreads();
    // 1024 16B-chunks per operand tile; wave stages [wave*256, wave*256+256)
    #pragma unroll
    for (int j = 0; j < 4; ++j) {
      int cbase = wave * 256 + j * 64;        // wave-uniform LDS base
      int c = cbase + lane;
      int row = c >> 3;
      int kcl = (c ^ row) & 7;                // xor-permuted chunk fetch
      gld_lds16(A  + (size_t)(m0 + row) * lda + k0 + kcl * 8, Ash + cbase * 8);
      gld_lds16(WT + (size_t)(n0 + row) * K   + k0 + kcl * 8, Bsh + cbase * 8);
    }
    __syncthreads();

    #pragma unroll
    for (int kk = 0; kk < 2; ++kk) {
      bf16x8 af[4], bfr[4];
      #pragma unroll
      for (int rb = 0; rb < 4; ++rb) {
        int row = wm * 64 + rb * 16 + c16;
        int kcp = ((kk * 4 + quad) ^ row) & 7;
        af[rb] = *(const bf16x8*)(Ash + row * 64 + kcp * 8);
      }
      #pragma unroll
      for (int nt = 0; nt < 4; ++nt) {
        int row = wn * 64 + nt * 16 + c16;
        int kcp = ((kk * 4 + quad) ^ row) & 7;
        bfr[nt] = *(const bf16x8*)(Bsh + row * 64 + kcp * 8);
      }
      #pragma unroll
      for (int rb = 0; rb < 4; ++rb)
        #pragma unroll
        for (int nt = 0; nt < 4; ++nt)
          acc[rb][nt] = __builtin_amdgcn_mfma_f32_16x16x32_bf16(af[rb], bfr[nt],
                                                                acc[rb][nt], 0, 0, 0);
    }
  }

  #pragma unroll
  for (int nt = 0; nt < 4; ++nt) {
    int col = n0 + wn * 64 + nt * 16 + c16;
    float bv = bias[col];
    #pragma unroll
    for (int rb = 0; rb < 4; ++rb) {
      int rbase = m0 + wm * 64 + rb * 16 + quad * 4;
      #pragma unroll
      for (int r = 0; r < 4; ++r)
        C[(size_t)(rbase + r) * ldc + col] = (OutT)(acc[rb][nt][r] + bv);
    }
  }
}

// ---------------------------------------------------------------------------
// Causal MQA attention, S^T formulation — QBLK-128 restructure (resubmit).
//
// History: round-3 version had a REAL bug (P overlay stride 68 elems = 136 B
// -> odd rows put ds_read_b128 at byte%16==8, misaligned DS access, faulted
// the container; round-4's "failed twice" is consistent with inheriting the
// poisoned container). Round-5 verified the container pool healthy. This is
// the round-4 source, re-audited (bounds/alignment/barrier-uniformity/
// swizzle-bijectivity/fragment-mapping all check), unchanged.
//
// Structure (vs verified round-2 parity-group version, attn ~100 us):
//  - QBLK 128 (8 waves = 8 q-strips), ONE 64-key K/V stream for all waves:
//    staged bytes per MFMA halved; no parity groups; merge phase deleted.
//  - LDS 71.7 -> 35 KB: K[64][136] ++ VT[128][72]; P overlays the K region
//    at stride 64 elems (128 B, 16B-aligned) with XOR chunk swizzle
//    (16B chunk c of row r at phys c^(r&7) — involution, so write and read
//    apply the same map); O overlays the whole pool after the loop.
//  - sacc reused as P (exp in place): -16 VGPR peak.
//  - load balance: per-block work ~ (2Q+2) tiles; Q = b ? 15-qh : qh with
//    qh=(x+h)&15 — the two blocks differing only in b sum to 34 tiles.
//  - T13 defer-max + T5 setprio kept (verified rounds 1-2).
// ---------------------------------------------------------------------------
__global__ __launch_bounds__(512, 4) void mqa_attn_kernel(
    const bf16_t* __restrict__ qkv, const bf16_t* __restrict__ vtg,
    bf16_t* __restrict__ out)
{
  __shared__ bf16_t sh[17920];           // 35840 B
  bf16_t* Ksh  = sh;                     // [64][136]  keys x d
  bf16_t* VTsh = sh + 64 * 136;          // [128][72]  d x keys
  // P overlays Ksh region: [128][64] q x keys, XOR-chunk-swizzled
  // O overlays sh[0..17408): [128][136] q x d

  const int tid  = threadIdx.x;
  const int wv   = tid >> 6;             // 0..7 : q-strip
  const int lane = tid & 63;
  const int quad = lane >> 4;
  const int c16  = lane & 15;
  const int h = blockIdx.y;
  const int b = blockIdx.z;
  const float qscale = 0.08838834764831845f * 1.4426950408889634f; // /sqrt(128)*log2e

  const bf16_t* kbase = qkv + (size_t)b * S_LEN * QKVN + HID;
  const bf16_t* vtb   = vtg + (size_t)b * HD * S_LEN;

  const int qh = ((int)blockIdx.x + h) & 15;
  const int Q  = b ? (15 - qh) : qh;     // balanced pairing across batch axis
  const int q0 = Q * 128;
  const int qrow = q0 + wv * 16 + c16;
  const int ntile = 2 * Q + 2;           // 64-key tiles to process

  const bf16_t* qp = qkv + ((size_t)(b * S_LEN + qrow)) * QKVN + h * HD;
  bf16x8 qf[4];
  #pragma unroll
  for (int ks = 0; ks < 4; ++ks) {
    bf16x8 t = *(const bf16x8*)(qp + ks * 32 + quad * 8);
    #pragma unroll
    for (int j = 0; j < 8; ++j) t[j] = (bf16_t)((float)t[j] * qscale);
    qf[ks] = t;
  }

  float m_q = NEG_BIG, l_q = 0.0f;
  f32x4 o[8] = {};

  // P-overlay addressing (row-private, swizzled; all offsets 16B-aligned)
  const int prow = wv * 16 + c16;
  bf16_t* Pbase = sh + (size_t)prow * 64;
  const int rsw = prow & 7;

  for (int kt = 0; kt < ntile; ++kt) {
    __syncthreads();   // prior iteration's P/PV reads done
    {
      const bf16_t* kb = kbase + (size_t)kt * 64 * QKVN;
      const bf16_t* vb = vtb + kt * 64;
      #pragma unroll
      for (int i = 0; i < 2; ++i) {
        int c = tid + i * 512;
        int key = c >> 4, dc = (c & 15) * 8;
        *(bf16x8*)(&Ksh[key * 136 + dc]) =
            *(const bf16x8*)(kb + (size_t)key * QKVN + dc);
      }
      #pragma unroll
      for (int i = 0; i < 2; ++i) {
        int c = tid + i * 512;
        int d = c >> 3, kc = (c & 7) * 8;
        *(bf16x8*)(&VTsh[d * 72 + kc]) =
            *(const bf16x8*)(vb + (size_t)d * S_LEN + kc);
      }
    }
    __syncthreads();

    const bool wactive = (kt * 64) <= (q0 + wv * 16 + 15);
    f32x4 sacc[4] = {};
    if (wactive) {
      __builtin_amdgcn_s_setprio(1);
      #pragma unroll
      for (int mt = 0; mt < 4; ++mt) {
        #pragma unroll
        for (int ks = 0; ks < 4; ++ks) {
          bf16x8 kf = *(const bf16x8*)(&Ksh[(mt * 16 + c16) * 136 + ks * 32 + quad * 8]);
          sacc[mt] = __builtin_amdgcn_mfma_f32_16x16x32_bf16(kf, qf[ks], sacc[mt], 0, 0, 0);
        }
      }
      __builtin_amdgcn_s_setprio(0);

      float mx = NEG_BIG;
      if (kt * 64 + 63 > q0 + wv * 16) {   // diagonal tile for this wave
        #pragma unroll
        for (int mt = 0; mt < 4; ++mt) {
          #pragma unroll
          for (int r = 0; r < 4; ++r) {
            int key = kt * 64 + mt * 16 + quad * 4 + r;
            float v = sacc[mt][r];
            if (key > qrow) v = NEG_BIG;
            sacc[mt][r] = v;
            mx = fmaxf(mx, v);
          }
        }
      } else {
        #pragma unroll
        for (int mt = 0; mt < 4; ++mt) {
          #pragma unroll
          for (int r = 0; r < 4; ++r) mx = fmaxf(mx, sacc[mt][r]);
        }
      }
      mx = fmaxf(mx, __shfl_xor(mx, 16));
      mx = fmaxf(mx, __shfl_xor(mx, 32));

      // T13 defer-max: only rescale when the running max grew by >THR.
      if (__any(mx > m_q + RESCALE_THR)) {
        float mn = fmaxf(m_q, mx);
        float alpha = __builtin_exp2f(m_q - mn);
        m_q = mn;
        l_q *= alpha;
        #pragma unroll
        for (int mt8 = 0; mt8 < 8; ++mt8) {
          #pragma unroll
          for (int r = 0; r < 4; ++r) o[mt8][r] *= alpha;
        }
      }

      float rs = 0.f;
      #pragma unroll
      for (int mt = 0; mt < 4; ++mt) {
        #pragma unroll
        for (int r = 0; r < 4; ++r) {
          float pe = __builtin_exp2f(sacc[mt][r] - m_q);
          sacc[mt][r] = pe;
          rs += pe;
        }
      }
      rs += __shfl_xor(rs, 16);
      rs += __shfl_xor(rs, 32);
      l_q += rs;
    }

    __syncthreads();   // all K-tile reads done -> Ksh region reusable as P
    if (wactive) {
      // P write: value for key = mt*16 + quad*4 + r -> logical 16B chunk
      // ch = 2*mt + (quad>>1), phys chunk ch^(row&7), within-chunk half
      // (quad&1)*4. bf16x4 = 8B stores, 8B-aligned.
      #pragma unroll
      for (int mt = 0; mt < 4; ++mt) {
        bf16x4 pk;
        #pragma unroll
        for (int r = 0; r < 4; ++r) pk[r] = (bf16_t)sacc[mt][r];
        int ch = 2 * mt + (quad >> 1);
        *(bf16x4*)(Pbase + (((ch ^ rsw) << 3) + (quad & 1) * 4)) = pk;
      }
      // P read: B-fragment keys kh*32+quad*8.. -> logical chunk 4*kh+quad,
      // 16B-aligned b128 at phys ^(row&7) (same involution).
      bf16x8 pf[2];
      #pragma unroll
      for (int kh = 0; kh < 2; ++kh) {
        int ch = 4 * kh + quad;
        pf[kh] = *(const bf16x8*)(Pbase + ((ch ^ rsw) << 3));
      }
      __builtin_amdgcn_s_setprio(1);
      #pragma unroll
      for (int mt8 = 0; mt8 < 8; ++mt8) {
        #pragma unroll
        for (int kh = 0; kh < 2; ++kh) {
          bf16x8 vf = *(const bf16x8*)(&VTsh[(mt8 * 16 + c16) * 72 + kh * 32 + quad * 8]);
          o[mt8] = __builtin_amdgcn_mfma_f32_16x16x32_bf16(vf, pf[kh], o[mt8], 0, 0, 0);
        }
      }
      __builtin_amdgcn_s_setprio(0);
    }
  }

  // ---- normalize + coalesced store via O overlay ----
  __syncthreads();   // all VTsh/P reads done; whole pool reusable as O
  float inv = 1.0f / fmaxf(l_q, 1e-20f);
  bf16_t* Osh = sh;  // [128][136]
  #pragma unroll
  for (int mt8 = 0; mt8 < 8; ++mt8) {
    bf16x4 pk;
    #pragma unroll
    for (int r = 0; r < 4; ++r) pk[r] = (bf16_t)(o[mt8][r] * inv);
    *(bf16x4*)(&Osh[(size_t)prow * 136 + mt8 * 16 + quad * 4]) = pk;
  }
  // rows are wave-private; compiler inserts the lgkmcnt for the DS RAW
  int ql = lane >> 2, dc = lane & 3;
  #pragma unroll
  for (int i = 0; i < 4; ++i) {
    bf16x8 v = *(const bf16x8*)(&Osh[(size_t)(wv * 16 + ql) * 136 + dc * 8 + i * 32]);
    *(bf16x8*)(out + ((size_t)(b * S_LEN + q0 + wv * 16 + ql)) * HID
                   + h * HD + dc * 8 + i * 32) = v;
  }
}

extern "C" void kernel_launch(void* const* d_in, const int* in_sizes, int n_in,
                              void* d_out, int out_size, void* d_ws, size_t ws_size,
                              hipStream_t stream) {
  const float* hidden_f   = (const float*)d_in[0];
  // d_in[1] = attention_mask (deterministic causal) -- ignored
  const float* c_attn_w_f = (const float*)d_in[2];
  const float* c_attn_b_f = (const float*)d_in[3];
  const float* c_proj_w_f = (const float*)d_in[4];
  const float* c_proj_b_f = (const float*)d_in[5];
  float* out = (float*)d_out;

  const int M = 2 * S_LEN;                 // 4096
  const int nH  = M * HID;
  const int nWq = HID * QKVN;
  const int nWp = HID * HID;

  bf16_t* hbf   = (bf16_t*)d_ws;
  bf16_t* wqT   = hbf  + nH;               // WT_qkv [2304][2048]
  bf16_t* wpT   = wqT  + nWq;              // WT_proj[2048][2048]
  bf16_t* qkv   = wpT  + nWp;              // [4096][2304]
  bf16_t* attn  = qkv  + (size_t)M * QKVN; // [4096][2048]
  bf16_t* vtg   = attn + (size_t)M * HID;  // V^T [2][128][2048]

  cvt_f32_bf16_kernel<<<nH / 1024, 256, 0, stream>>>(hidden_f, hbf, nH);
  dim3 gt1(QKVN / 64, HID / 32);
  transpose_cvt_kernel<<<gt1, 256, 0, stream>>>(c_attn_w_f, wqT, HID, QKVN);
  dim3 gt2(HID / 64, HID / 32);
  transpose_cvt_kernel<<<gt2, 256, 0, stream>>>(c_proj_w_f, wpT, HID, HID);

  dim3 g1(QKVN / 128, M / 128);
  gemm_bias_kernel<bf16_t><<<g1, 256, 0, stream>>>(hbf, wqT, c_attn_b_f, qkv,
                                                   HID, HID, QKVN);

  dim3 gv(S_LEN / 16, 2);
  vt_extract_kernel<<<gv, 256, 0, stream>>>(qkv, vtg);

  dim3 g2(16, NH, 2);
  mqa_attn_kernel<<<g2, 512, 0, stream>>>(qkv, vtg, attn);

  dim3 g3(HID / 128, M / 128);
  gemm_bias_kernel<float><<<g3, 256, 0, stream>>>(attn, wpT, c_proj_b_f, out,
                                                  HID, HID, HID);
}

// Round 7
// 311.024 us; speedup vs baseline: 1.2389x; 1.0727x over previous
//
#include <hip/hip_runtime.h>
#include <hip/hip_bf16.h>

typedef __bf16 bf16_t;
typedef __bf16 bf16x8 __attribute__((ext_vector_type(8)));
typedef __bf16 bf16x4 __attribute__((ext_vector_type(4)));
typedef float f32x4 __attribute__((ext_vector_type(4)));

#define S_LEN 2048
#define HID   2048
#define NH    16
#define HD    128
#define QKVN  2304   // 2048 + 2*128
#define NEG_BIG (-30000.0f)
#define RESCALE_THR 8.0f

// direct global->LDS DMA, 16B per lane. lds dst must be the WAVE-UNIFORM base;
// HW adds lane*16 itself (m104). No LDS padding allowed in the covered range.
__device__ __forceinline__ void gld_lds16(const bf16_t* g, bf16_t* l) {
  __builtin_amdgcn_global_load_lds(
      (const __attribute__((address_space(1))) void*)((const void*)g),
      (__attribute__((address_space(3))) void*)((void*)l), 16, 0, 0);
}

// ---------------------------------------------------------------------------
// fp32 -> bf16 downcast, float4-vectorized.
// ---------------------------------------------------------------------------
__global__ __launch_bounds__(256) void cvt_f32_bf16_kernel(
    const float* __restrict__ in, bf16_t* __restrict__ out, int n)
{
  int i = (blockIdx.x * 256 + threadIdx.x) * 4;
  if (i < n) {
    float4 v = *(const float4*)(in + i);
    bf16x4 o;
    o[0] = (bf16_t)v.x; o[1] = (bf16_t)v.y; o[2] = (bf16_t)v.z; o[3] = (bf16_t)v.w;
    *(bf16x4*)(out + i) = o;
  }
}

// ---------------------------------------------------------------------------
// fp32 W[K][N] -> bf16 WT[N][K].
// ---------------------------------------------------------------------------
__global__ __launch_bounds__(256) void transpose_cvt_kernel(
    const float* __restrict__ in, bf16_t* __restrict__ out, int K, int N)
{
  int nc = threadIdx.x & 63;
  int kg = threadIdx.x >> 6;
  int n  = blockIdx.x * 64 + nc;
  int kb = blockIdx.y * 32 + kg * 8;
  bf16x8 v;
  #pragma unroll
  for (int i = 0; i < 8; ++i) v[i] = (bf16_t)in[(size_t)(kb + i) * N + n];
  *(bf16x8*)(out + (size_t)n * K + kb) = v;
}

// ---------------------------------------------------------------------------
// Extract V^T from qkv: vtg[b][d][s] = qkv[b*S+s][2176+d].
// ---------------------------------------------------------------------------
__global__ __launch_bounds__(256) void vt_extract_kernel(
    const bf16_t* __restrict__ qkv, bf16_t* __restrict__ vtg)
{
  int d  = threadIdx.x & 127;
  int sg = threadIdx.x >> 7;
  int b  = blockIdx.y;
  int s8 = blockIdx.x * 2 + sg;
  bf16x8 v;
  #pragma unroll
  for (int i = 0; i < 8; ++i)
    v[i] = qkv[((size_t)(b * S_LEN + s8 * 8 + i)) * QKVN + HID + HD + d];
  *(bf16x8*)(vtg + ((size_t)(b * HD + d)) * S_LEN + s8 * 8) = v;
}

// ---------------------------------------------------------------------------
// GEMM: C[M,N] = A[M,K] @ WT^T + bias (WT pre-transposed [N][K]).
// 128x128 C-tile, BK=64, 4 waves as 2x2 (wave owns 64x64, acc[4][4]).
// T1 XCD-aware block swizzle (verified round 5). (unchanged)
// ---------------------------------------------------------------------------
template <typename OutT>
__global__ __launch_bounds__(256) void gemm_bias_kernel(
    const bf16_t* __restrict__ A, const bf16_t* __restrict__ WT,
    const float* __restrict__ bias, OutT* __restrict__ C,
    int K, int lda, int ldc)
{
  __shared__ bf16_t Ash[128 * 64];   // [m][k] swizzled, NO padding (lds-dma)
  __shared__ bf16_t Bsh[128 * 64];   // [n][k] swizzled, NO padding

  const int tid  = threadIdx.x;
  const int wave = tid >> 6;
  const int lane = tid & 63;
  const int quad = lane >> 4;
  const int c16  = lane & 15;
  const int wm = wave >> 1;          // 0..1 : row half
  const int wn = wave & 1;           // 0..1 : col half

  // T1 XCD swizzle: id -> (id%8)*cpx + id/8, bijective when nwg%8==0.
  int id  = (int)(blockIdx.y * gridDim.x + blockIdx.x);
  int nwg = (int)(gridDim.x * gridDim.y);
  int swz = (nwg & 7) ? id : ((id & 7) * (nwg >> 3) + (id >> 3));
  const int n0 = (swz % (int)gridDim.x) * 128;
  const int m0 = (swz / (int)gridDim.x) * 128;

  f32x4 acc[4][4] = {};

  for (int k0 = 0; k0 < K; k0 += 64) {
    __syncthreads();
    // 1024 16B-chunks per operand tile; wave stages [wave*256, wave*256+256)
    #pragma unroll
    for (int j = 0; j < 4; ++j) {
      int cbase = wave * 256 + j * 64;        // wave-uniform LDS base
      int c = cbase + lane;
      int row = c >> 3;
      int kcl = (c ^ row) & 7;                // xor-permuted chunk fetch
      gld_lds16(A  + (size_t)(m0 + row) * lda + k0 + kcl * 8, Ash + cbase * 8);
      gld_lds16(WT + (size_t)(n0 + row) * K   + k0 + kcl * 8, Bsh + cbase * 8);
    }
    __syncthreads();

    #pragma unroll
    for (int kk = 0; kk < 2; ++kk) {
      bf16x8 af[4], bfr[4];
      #pragma unroll
      for (int rb = 0; rb < 4; ++rb) {
        int row = wm * 64 + rb * 16 + c16;
        int kcp = ((kk * 4 + quad) ^ row) & 7;
        af[rb] = *(const bf16x8*)(Ash + row * 64 + kcp * 8);
      }
      #pragma unroll
      for (int nt = 0; nt < 4; ++nt) {
        int row = wn * 64 + nt * 16 + c16;
        int kcp = ((kk * 4 + quad) ^ row) & 7;
        bfr[nt] = *(const bf16x8*)(Bsh + row * 64 + kcp * 8);
      }
      #pragma unroll
      for (int rb = 0; rb < 4; ++rb)
        #pragma unroll
        for (int nt = 0; nt < 4; ++nt)
          acc[rb][nt] = __builtin_amdgcn_mfma_f32_16x16x32_bf16(af[rb], bfr[nt],
                                                                acc[rb][nt], 0, 0, 0);
    }
  }

  #pragma unroll
  for (int nt = 0; nt < 4; ++nt) {
    int col = n0 + wn * 64 + nt * 16 + c16;
    float bv = bias[col];
    #pragma unroll
    for (int rb = 0; rb < 4; ++rb) {
      int rbase = m0 + wm * 64 + rb * 16 + quad * 4;
      #pragma unroll
      for (int r = 0; r < 4; ++r)
        C[(size_t)(rbase + r) * ldc + col] = (OutT)(acc[rb][nt][r] + bv);
    }
  }
}

// ---------------------------------------------------------------------------
// Causal MQA attention, S^T formulation, QBLK=128, 8 waves.
//
// Round-7 schedule (round-6 post-mortem: MfmaUtil 15%, 3 full-drain barriers
// per tile + register-roundtrip staging between two of them = serial chain;
// occupancy grid-capped at 2 blocks/CU so LDS below 80 KB is free):
//  - P gets a DEDICATED 16 KB region (wave-private rows) -> the mid-tile
//    barrier (existed only because P overlaid Ksh) is deleted.
//  - K/V double-buffered and staged via global_load_lds DMA (zero VGPR,
//    no ds_writes). DMA for tile kt+1 is issued right AFTER the single
//    __syncthreads; the NEXT iteration's __syncthreads (vmcnt(0)+barrier,
//    HIP semantics) is exactly its completion wait. ONE barrier per tile,
//    staging latency hidden under a full tile of compute.
//  - DMA needs linear LDS: K[64][128], VT[128][64], both with T2 XOR chunk
//    swizzle (16B chunk c of row r at phys c^(r&7); source pre-swizzled
//    per-lane, same proven pattern as the GEMM staging). Reads: 2-way bank
//    aliasing = free (m136).
//  - LDS 80 KB: K 2x16 + VT 2x16 + P 16; O overlay after final barrier.
//  - T13 defer-max + T5 setprio kept; load-balance pairing kept.
// ---------------------------------------------------------------------------
__global__ __launch_bounds__(512, 4) void mqa_attn_kernel(
    const bf16_t* __restrict__ qkv, const bf16_t* __restrict__ vtg,
    bf16_t* __restrict__ out)
{
  __shared__ bf16_t sh[40960];           // 81920 B
  // K[buf]  = sh + buf*8192           : [64][128]  keys x d   (swizzled)
  // VT[buf] = sh + 16384 + buf*8192   : [128][64]  d x keys   (swizzled)
  // P       = sh + 32768              : [128][64]  q x keys   (swizzled)
  // O overlay over sh[0..17408) after the loop.

  const int tid  = threadIdx.x;
  const int wv   = tid >> 6;             // 0..7 : q-strip
  const int lane = tid & 63;
  const int quad = lane >> 4;
  const int c16  = lane & 15;
  const int h = blockIdx.y;
  const int b = blockIdx.z;
  const float qscale = 0.08838834764831845f * 1.4426950408889634f; // /sqrt(128)*log2e

  const bf16_t* kbase = qkv + (size_t)b * S_LEN * QKVN + HID;
  const bf16_t* vtb   = vtg + (size_t)b * HD * S_LEN;

  const int qh = ((int)blockIdx.x + h) & 15;
  const int Q  = b ? (15 - qh) : qh;     // balanced pairing across batch axis
  const int q0 = Q * 128;
  const int qrow = q0 + wv * 16 + c16;
  const int ntile = 2 * Q + 2;           // 64-key tiles to process

  const bf16_t* qp = qkv + ((size_t)(b * S_LEN + qrow)) * QKVN + h * HD;
  bf16x8 qf[4];
  #pragma unroll
  for (int ks = 0; ks < 4; ++ks) {
    bf16x8 t = *(const bf16x8*)(qp + ks * 32 + quad * 8);
    #pragma unroll
    for (int j = 0; j < 8; ++j) t[j] = (bf16_t)((float)t[j] * qscale);
    qf[ks] = t;
  }

  float m_q = NEG_BIG, l_q = 0.0f;
  f32x4 o[8] = {};

  // P addressing (dedicated region, wave-private rows, XOR chunk swizzle)
  const int prow = wv * 16 + c16;
  const int rsw  = prow & 7;
  bf16_t* Pbase = sh + 32768 + (size_t)prow * 64;

  // DMA staging: K = 1024 chunks (64 rows x 16), VT = 1024 chunks (128 x 8).
  // Slot c holds source chunk (c&mask)^(row&7) of its row -> reads below
  // apply the same involution. LDS dst is the wave-uniform base (c & ~63).
  #define STAGE(bufi, kti) do {                                              \
    const bf16_t* kb_ = kbase + (size_t)(kti) * 64 * QKVN;                   \
    const bf16_t* vb_ = vtb + (kti) * 64;                                    \
    bf16_t* Kd_ = sh + (bufi) * 8192;                                        \
    bf16_t* Vd_ = sh + 16384 + (bufi) * 8192;                                \
    _Pragma("unroll")                                                        \
    for (int i_ = 0; i_ < 2; ++i_) {                                         \
      int c_ = tid + i_ * 512;                                               \
      int r_ = c_ >> 4, lc_ = (c_ & 15) ^ (r_ & 7);                          \
      gld_lds16(kb_ + (size_t)r_ * QKVN + lc_ * 8, Kd_ + (c_ & ~63) * 8);    \
    }                                                                        \
    _Pragma("unroll")                                                        \
    for (int i_ = 0; i_ < 2; ++i_) {                                         \
      int c_ = tid + i_ * 512;                                               \
      int r_ = c_ >> 3, lc_ = (c_ & 7) ^ (r_ & 7);                           \
      gld_lds16(vb_ + (size_t)r_ * S_LEN + lc_ * 8, Vd_ + (c_ & ~63) * 8);   \
    }                                                                        \
  } while (0)

  STAGE(0, 0);
  int cur = 0;

  for (int kt = 0; kt < ntile; ++kt) {
    // HIP __syncthreads = s_waitcnt vmcnt(0) lgkmcnt(0) + s_barrier:
    // completes buf[cur]'s DMA (issued one tile ago) AND rendezvous so the
    // DMA issued below may overwrite the buffer read last iteration.
    __syncthreads();
    if (kt + 1 < ntile) STAGE(cur ^ 1, kt + 1);

    const bf16_t* Kc = sh + cur * 8192;
    const bf16_t* Vc = sh + 16384 + cur * 8192;
    const bool wactive = (kt * 64) <= (q0 + wv * 16 + 15);
    if (wactive) {
      f32x4 sacc[4] = {};
      __builtin_amdgcn_s_setprio(1);
      #pragma unroll
      for (int mt = 0; mt < 4; ++mt) {
        int krow = mt * 16 + c16;
        #pragma unroll
        for (int ks = 0; ks < 4; ++ks) {
          bf16x8 kf = *(const bf16x8*)(Kc + krow * 128 +
                                       (((ks * 4 + quad) ^ (krow & 7)) << 3));
          sacc[mt] = __builtin_amdgcn_mfma_f32_16x16x32_bf16(kf, qf[ks], sacc[mt], 0, 0, 0);
        }
      }
      __builtin_amdgcn_s_setprio(0);

      float mx = NEG_BIG;
      if (kt * 64 + 63 > q0 + wv * 16) {   // diagonal tile for this wave
        #pragma unroll
        for (int mt = 0; mt < 4; ++mt) {
          #pragma unroll
          for (int r = 0; r < 4; ++r) {
            int key = kt * 64 + mt * 16 + quad * 4 + r;
            float v = sacc[mt][r];
            if (key > qrow) v = NEG_BIG;
            sacc[mt][r] = v;
            mx = fmaxf(mx, v);
          }
        }
      } else {
        #pragma unroll
        for (int mt = 0; mt < 4; ++mt) {
          #pragma unroll
          for (int r = 0; r < 4; ++r) mx = fmaxf(mx, sacc[mt][r]);
        }
      }
      mx = fmaxf(mx, __shfl_xor(mx, 16));
      mx = fmaxf(mx, __shfl_xor(mx, 32));

      // T13 defer-max: only rescale when the running max grew by >THR.
      if (__any(mx > m_q + RESCALE_THR)) {
        float mn = fmaxf(m_q, mx);
        float alpha = __builtin_exp2f(m_q - mn);
        m_q = mn;
        l_q *= alpha;
        #pragma unroll
        for (int mt8 = 0; mt8 < 8; ++mt8) {
          #pragma unroll
          for (int r = 0; r < 4; ++r) o[mt8][r] *= alpha;
        }
      }

      float rs = 0.f;
      #pragma unroll
      for (int mt = 0; mt < 4; ++mt) {
        #pragma unroll
        for (int r = 0; r < 4; ++r) {
          float pe = __builtin_exp2f(sacc[mt][r] - m_q);
          sacc[mt][r] = pe;
          rs += pe;
        }
      }
      rs += __shfl_xor(rs, 16);
      rs += __shfl_xor(rs, 32);
      l_q += rs;

      // P write (wave-private rows -> NO barrier): key = mt*16+quad*4+r
      // -> logical chunk 2*mt+(quad>>1), phys ^rsw, half (quad&1)*4.
      #pragma unroll
      for (int mt = 0; mt < 4; ++mt) {
        bf16x4 pk;
        #pragma unroll
        for (int r = 0; r < 4; ++r) pk[r] = (bf16_t)sacc[mt][r];
        int ch = 2 * mt + (quad >> 1);
        *(bf16x4*)(Pbase + (((ch ^ rsw) << 3) + (quad & 1) * 4)) = pk;
      }
      // P read: logical chunk 4*kh+quad, same involution, 16B-aligned.
      bf16x8 pf[2];
      #pragma unroll
      for (int kh = 0; kh < 2; ++kh)
        pf[kh] = *(const bf16x8*)(Pbase + (((4 * kh + quad) ^ rsw) << 3));

      __builtin_amdgcn_s_setprio(1);
      #pragma unroll
      for (int mt8 = 0; mt8 < 8; ++mt8) {
        int vrow = mt8 * 16 + c16;
        #pragma unroll
        for (int kh = 0; kh < 2; ++kh) {
          bf16x8 vf = *(const bf16x8*)(Vc + vrow * 64 +
                                       (((kh * 4 + quad) ^ (vrow & 7)) << 3));
          o[mt8] = __builtin_amdgcn_mfma_f32_16x16x32_bf16(vf, pf[kh], o[mt8], 0, 0, 0);
        }
      }
      __builtin_amdgcn_s_setprio(0);
    }
    cur ^= 1;
  }
  #undef STAGE

  // ---- normalize + coalesced store via O overlay ----
  __syncthreads();   // all K/VT/P reads done; pool reusable as O
  float inv = 1.0f / fmaxf(l_q, 1e-20f);
  bf16_t* Osh = sh;  // [128][136]
  #pragma unroll
  for (int mt8 = 0; mt8 < 8; ++mt8) {
    bf16x4 pk;
    #pragma unroll
    for (int r = 0; r < 4; ++r) pk[r] = (bf16_t)(o[mt8][r] * inv);
    *(bf16x4*)(&Osh[(size_t)prow * 136 + mt8 * 16 + quad * 4]) = pk;
  }
  // rows are wave-private; compiler inserts the lgkmcnt for the DS RAW
  int ql = lane >> 2, dc = lane & 3;
  #pragma unroll
  for (int i = 0; i < 4; ++i) {
    bf16x8 v = *(const bf16x8*)(&Osh[(size_t)(wv * 16 + ql) * 136 + dc * 8 + i * 32]);
    *(bf16x8*)(out + ((size_t)(b * S_LEN + q0 + wv * 16 + ql)) * HID
                   + h * HD + dc * 8 + i * 32) = v;
  }
}

extern "C" void kernel_launch(void* const* d_in, const int* in_sizes, int n_in,
                              void* d_out, int out_size, void* d_ws, size_t ws_size,
                              hipStream_t stream) {
  const float* hidden_f   = (const float*)d_in[0];
  // d_in[1] = attention_mask (deterministic causal) -- ignored
  const float* c_attn_w_f = (const float*)d_in[2];
  const float* c_attn_b_f = (const float*)d_in[3];
  const float* c_proj_w_f = (const float*)d_in[4];
  const float* c_proj_b_f = (const float*)d_in[5];
  float* out = (float*)d_out;

  const int M = 2 * S_LEN;                 // 4096
  const int nH  = M * HID;
  const int nWq = HID * QKVN;
  const int nWp = HID * HID;

  bf16_t* hbf   = (bf16_t*)d_ws;
  bf16_t* wqT   = hbf  + nH;               // WT_qkv [2304][2048]
  bf16_t* wpT   = wqT  + nWq;              // WT_proj[2048][2048]
  bf16_t* qkv   = wpT  + nWp;              // [4096][2304]
  bf16_t* attn  = qkv  + (size_t)M * QKVN; // [4096][2048]
  bf16_t* vtg   = attn + (size_t)M * HID;  // V^T [2][128][2048]

  cvt_f32_bf16_kernel<<<nH / 1024, 256, 0, stream>>>(hidden_f, hbf, nH);
  dim3 gt1(QKVN / 64, HID / 32);
  transpose_cvt_kernel<<<gt1, 256, 0, stream>>>(c_attn_w_f, wqT, HID, QKVN);
  dim3 gt2(HID / 64, HID / 32);
  transpose_cvt_kernel<<<gt2, 256, 0, stream>>>(c_proj_w_f, wpT, HID, HID);

  dim3 g1(QKVN / 128, M / 128);
  gemm_bias_kernel<bf16_t><<<g1, 256, 0, stream>>>(hbf, wqT, c_attn_b_f, qkv,
                                                   HID, HID, QKVN);

  dim3 gv(S_LEN / 16, 2);
  vt_extract_kernel<<<gv, 256, 0, stream>>>(qkv, vtg);

  dim3 g2(16, NH, 2);
  mqa_attn_kernel<<<g2, 512, 0, stream>>>(qkv, vtg, attn);

  dim3 g3(HID / 128, M / 128);
  gemm_bias_kernel<float><<<g3, 256, 0, stream>>>(attn, wpT, c_proj_b_f, out,
                                                  HID, HID, HID);
}

// Round 8
// 301.235 us; speedup vs baseline: 1.2792x; 1.0325x over previous
//
#include <hip/hip_runtime.h>
#include <hip/hip_bf16.h>

typedef __bf16 bf16_t;
typedef __bf16 bf16x8 __attribute__((ext_vector_type(8)));
typedef __bf16 bf16x4 __attribute__((ext_vector_type(4)));
typedef float f32x4 __attribute__((ext_vector_type(4)));

#define S_LEN 2048
#define HID   2048
#define NH    16
#define HD    128
#define QKVN  2304   // 2048 + 2*128
#define NEG_BIG (-30000.0f)
#define RESCALE_THR 8.0f

// direct global->LDS DMA, 16B per lane. lds dst must be the WAVE-UNIFORM base;
// HW adds lane*16 itself (m104). No LDS padding allowed in the covered range.
__device__ __forceinline__ void gld_lds16(const bf16_t* g, bf16_t* l) {
  __builtin_amdgcn_global_load_lds(
      (const __attribute__((address_space(1))) void*)((const void*)g),
      (__attribute__((address_space(3))) void*)((void*)l), 16, 0, 0);
}

// ---------------------------------------------------------------------------
// fp32 -> bf16 downcast, float4-vectorized.
// ---------------------------------------------------------------------------
__global__ __launch_bounds__(256) void cvt_f32_bf16_kernel(
    const float* __restrict__ in, bf16_t* __restrict__ out, int n)
{
  int i = (blockIdx.x * 256 + threadIdx.x) * 4;
  if (i < n) {
    float4 v = *(const float4*)(in + i);
    bf16x4 o;
    o[0] = (bf16_t)v.x; o[1] = (bf16_t)v.y; o[2] = (bf16_t)v.z; o[3] = (bf16_t)v.w;
    *(bf16x4*)(out + i) = o;
  }
}

// ---------------------------------------------------------------------------
// fp32 W[K][N] -> bf16 WT[N][K].
// ---------------------------------------------------------------------------
__global__ __launch_bounds__(256) void transpose_cvt_kernel(
    const float* __restrict__ in, bf16_t* __restrict__ out, int K, int N)
{
  int nc = threadIdx.x & 63;
  int kg = threadIdx.x >> 6;
  int n  = blockIdx.x * 64 + nc;
  int kb = blockIdx.y * 32 + kg * 8;
  bf16x8 v;
  #pragma unroll
  for (int i = 0; i < 8; ++i) v[i] = (bf16_t)in[(size_t)(kb + i) * N + n];
  *(bf16x8*)(out + (size_t)n * K + kb) = v;
}

// ---------------------------------------------------------------------------
// Extract V^T from qkv: vtg[b][d][s] = qkv[b*S+s][2176+d].
// ---------------------------------------------------------------------------
__global__ __launch_bounds__(256) void vt_extract_kernel(
    const bf16_t* __restrict__ qkv, bf16_t* __restrict__ vtg)
{
  int d  = threadIdx.x & 127;
  int sg = threadIdx.x >> 7;
  int b  = blockIdx.y;
  int s8 = blockIdx.x * 2 + sg;
  bf16x8 v;
  #pragma unroll
  for (int i = 0; i < 8; ++i)
    v[i] = qkv[((size_t)(b * S_LEN + s8 * 8 + i)) * QKVN + HID + HD + d];
  *(bf16x8*)(vtg + ((size_t)(b * HD + d)) * S_LEN + s8 * 8) = v;
}

// ---------------------------------------------------------------------------
// GEMM: C[M,N] = A[M,K] @ WT^T + bias (WT pre-transposed [N][K]).
// 128x128 C-tile, BK=64, 4 waves as 2x2 (wave owns 64x64, acc[4][4]).
// T1 XCD-aware block swizzle (verified round 5).
//
// Round-8: port the round-7 attention schedule (verified) into the K-loop.
// Old: sync -> issue DMA -> sync -> compute  (vmcnt(0) drain right after
// issue = full L2/HBM latency exposed on every one of the K/64 steps; this
// is why MfmaUtil sat at 18%). New: double-buffered LDS (32->64 KB, free —
// grid caps residency at ~2 blocks/CU), prologue STAGE, then per K-step:
// sync (completes prev DMA + rendezvous) -> STAGE(next) -> compute(cur).
// ONE barrier per K-step; DMA latency hides under 32 MFMAs of compute.
// ---------------------------------------------------------------------------
template <typename OutT>
__global__ __launch_bounds__(256) void gemm_bias_kernel(
    const bf16_t* __restrict__ A, const bf16_t* __restrict__ WT,
    const float* __restrict__ bias, OutT* __restrict__ C,
    int K, int lda, int ldc)
{
  __shared__ bf16_t Ash[2 * 128 * 64];   // [buf][m][k] swizzled, NO padding
  __shared__ bf16_t Bsh[2 * 128 * 64];   // [buf][n][k] swizzled, NO padding

  const int tid  = threadIdx.x;
  const int wave = tid >> 6;
  const int lane = tid & 63;
  const int quad = lane >> 4;
  const int c16  = lane & 15;
  const int wm = wave >> 1;          // 0..1 : row half
  const int wn = wave & 1;           // 0..1 : col half

  // T1 XCD swizzle: id -> (id%8)*cpx + id/8, bijective when nwg%8==0.
  int id  = (int)(blockIdx.y * gridDim.x + blockIdx.x);
  int nwg = (int)(gridDim.x * gridDim.y);
  int swz = (nwg & 7) ? id : ((id & 7) * (nwg >> 3) + (id >> 3));
  const int n0 = (swz % (int)gridDim.x) * 128;
  const int m0 = (swz / (int)gridDim.x) * 128;

  f32x4 acc[4][4] = {};

  // 1024 16B-chunks per operand tile; wave stages [wave*256, wave*256+256).
  // Slot c holds global chunk (row=c>>3, kc=(c^row)&7) — XOR chunk fetch,
  // matching the swizzled read below. LDS dst is the wave-uniform base.
  #define GSTAGE(bufi, k0v) do {                                             \
    bf16_t* Ad_ = Ash + (bufi) * 8192;                                       \
    bf16_t* Bd_ = Bsh + (bufi) * 8192;                                       \
    _Pragma("unroll")                                                        \
    for (int j_ = 0; j_ < 4; ++j_) {                                         \
      int cbase_ = wave * 256 + j_ * 64;                                     \
      int c_ = cbase_ + lane;                                                \
      int row_ = c_ >> 3;                                                    \
      int kcl_ = (c_ ^ row_) & 7;                                            \
      gld_lds16(A  + (size_t)(m0 + row_) * lda + (k0v) + kcl_ * 8,           \
                Ad_ + cbase_ * 8);                                           \
      gld_lds16(WT + (size_t)(n0 + row_) * K   + (k0v) + kcl_ * 8,           \
                Bd_ + cbase_ * 8);                                           \
    }                                                                        \
  } while (0)

  GSTAGE(0, 0);
  int cur = 0;

  for (int k0 = 0; k0 < K; k0 += 64) {
    // __syncthreads = s_waitcnt vmcnt(0) lgkmcnt(0) + s_barrier: completes
    // buf[cur]'s DMA (issued one K-step ago) AND rendezvous so the DMA
    // issued below may overwrite the buffer read last step.
    __syncthreads();
    if (k0 + 64 < K) GSTAGE(cur ^ 1, k0 + 64);

    const bf16_t* Ac = Ash + cur * 8192;
    const bf16_t* Bc = Bsh + cur * 8192;
    #pragma unroll
    for (int kk = 0; kk < 2; ++kk) {
      bf16x8 af[4], bfr[4];
      #pragma unroll
      for (int rb = 0; rb < 4; ++rb) {
        int row = wm * 64 + rb * 16 + c16;
        int kcp = ((kk * 4 + quad) ^ row) & 7;
        af[rb] = *(const bf16x8*)(Ac + row * 64 + kcp * 8);
      }
      #pragma unroll
      for (int nt = 0; nt < 4; ++nt) {
        int row = wn * 64 + nt * 16 + c16;
        int kcp = ((kk * 4 + quad) ^ row) & 7;
        bfr[nt] = *(const bf16x8*)(Bc + row * 64 + kcp * 8);
      }
      #pragma unroll
      for (int rb = 0; rb < 4; ++rb)
        #pragma unroll
        for (int nt = 0; nt < 4; ++nt)
          acc[rb][nt] = __builtin_amdgcn_mfma_f32_16x16x32_bf16(af[rb], bfr[nt],
                                                                acc[rb][nt], 0, 0, 0);
    }
    cur ^= 1;
  }
  #undef GSTAGE

  #pragma unroll
  for (int nt = 0; nt < 4; ++nt) {
    int col = n0 + wn * 64 + nt * 16 + c16;
    float bv = bias[col];
    #pragma unroll
    for (int rb = 0; rb < 4; ++rb) {
      int rbase = m0 + wm * 64 + rb * 16 + quad * 4;
      #pragma unroll
      for (int r = 0; r < 4; ++r)
        C[(size_t)(rbase + r) * ldc + col] = (OutT)(acc[rb][nt][r] + bv);
    }
  }
}

// ---------------------------------------------------------------------------
// Causal MQA attention, S^T formulation, QBLK=128, 8 waves.
// (verified round 7 — unchanged: single barrier per tile, double-buffered
// global_load_lds DMA staging, dedicated P region, T13 + T5, load-balance
// pairing. attn ~<=65 us, no longer the top dispatch.)
// ---------------------------------------------------------------------------
__global__ __launch_bounds__(512, 4) void mqa_attn_kernel(
    const bf16_t* __restrict__ qkv, const bf16_t* __restrict__ vtg,
    bf16_t* __restrict__ out)
{
  __shared__ bf16_t sh[40960];           // 81920 B
  // K[buf]  = sh + buf*8192           : [64][128]  keys x d   (swizzled)
  // VT[buf] = sh + 16384 + buf*8192   : [128][64]  d x keys   (swizzled)
  // P       = sh + 32768              : [128][64]  q x keys   (swizzled)
  // O overlay over sh[0..17408) after the loop.

  const int tid  = threadIdx.x;
  const int wv   = tid >> 6;             // 0..7 : q-strip
  const int lane = tid & 63;
  const int quad = lane >> 4;
  const int c16  = lane & 15;
  const int h = blockIdx.y;
  const int b = blockIdx.z;
  const float qscale = 0.08838834764831845f * 1.4426950408889634f; // /sqrt(128)*log2e

  const bf16_t* kbase = qkv + (size_t)b * S_LEN * QKVN + HID;
  const bf16_t* vtb   = vtg + (size_t)b * HD * S_LEN;

  const int qh = ((int)blockIdx.x + h) & 15;
  const int Q  = b ? (15 - qh) : qh;     // balanced pairing across batch axis
  const int q0 = Q * 128;
  const int qrow = q0 + wv * 16 + c16;
  const int ntile = 2 * Q + 2;           // 64-key tiles to process

  const bf16_t* qp = qkv + ((size_t)(b * S_LEN + qrow)) * QKVN + h * HD;
  bf16x8 qf[4];
  #pragma unroll
  for (int ks = 0; ks < 4; ++ks) {
    bf16x8 t = *(const bf16x8*)(qp + ks * 32 + quad * 8);
    #pragma unroll
    for (int j = 0; j < 8; ++j) t[j] = (bf16_t)((float)t[j] * qscale);
    qf[ks] = t;
  }

  float m_q = NEG_BIG, l_q = 0.0f;
  f32x4 o[8] = {};

  // P addressing (dedicated region, wave-private rows, XOR chunk swizzle)
  const int prow = wv * 16 + c16;
  const int rsw  = prow & 7;
  bf16_t* Pbase = sh + 32768 + (size_t)prow * 64;

  // DMA staging: K = 1024 chunks (64 rows x 16), VT = 1024 chunks (128 x 8).
  // Slot c holds source chunk (c&mask)^(row&7) of its row -> reads below
  // apply the same involution. LDS dst is the wave-uniform base (c & ~63).
  #define STAGE(bufi, kti) do {                                              \
    const bf16_t* kb_ = kbase + (size_t)(kti) * 64 * QKVN;                   \
    const bf16_t* vb_ = vtb + (kti) * 64;                                    \
    bf16_t* Kd_ = sh + (bufi) * 8192;                                        \
    bf16_t* Vd_ = sh + 16384 + (bufi) * 8192;                                \
    _Pragma("unroll")                                                        \
    for (int i_ = 0; i_ < 2; ++i_) {                                         \
      int c_ = tid + i_ * 512;                                               \
      int r_ = c_ >> 4, lc_ = (c_ & 15) ^ (r_ & 7);                          \
      gld_lds16(kb_ + (size_t)r_ * QKVN + lc_ * 8, Kd_ + (c_ & ~63) * 8);    \
    }                                                                        \
    _Pragma("unroll")                                                        \
    for (int i_ = 0; i_ < 2; ++i_) {                                         \
      int c_ = tid + i_ * 512;                                               \
      int r_ = c_ >> 3, lc_ = (c_ & 7) ^ (r_ & 7);                           \
      gld_lds16(vb_ + (size_t)r_ * S_LEN + lc_ * 8, Vd_ + (c_ & ~63) * 8);   \
    }                                                                        \
  } while (0)

  STAGE(0, 0);
  int cur = 0;

  for (int kt = 0; kt < ntile; ++kt) {
    // HIP __syncthreads = s_waitcnt vmcnt(0) lgkmcnt(0) + s_barrier:
    // completes buf[cur]'s DMA (issued one tile ago) AND rendezvous so the
    // DMA issued below may overwrite the buffer read last iteration.
    __syncthreads();
    if (kt + 1 < ntile) STAGE(cur ^ 1, kt + 1);

    const bf16_t* Kc = sh + cur * 8192;
    const bf16_t* Vc = sh + 16384 + cur * 8192;
    const bool wactive = (kt * 64) <= (q0 + wv * 16 + 15);
    if (wactive) {
      f32x4 sacc[4] = {};
      __builtin_amdgcn_s_setprio(1);
      #pragma unroll
      for (int mt = 0; mt < 4; ++mt) {
        int krow = mt * 16 + c16;
        #pragma unroll
        for (int ks = 0; ks < 4; ++ks) {
          bf16x8 kf = *(const bf16x8*)(Kc + krow * 128 +
                                       (((ks * 4 + quad) ^ (krow & 7)) << 3));
          sacc[mt] = __builtin_amdgcn_mfma_f32_16x16x32_bf16(kf, qf[ks], sacc[mt], 0, 0, 0);
        }
      }
      __builtin_amdgcn_s_setprio(0);

      float mx = NEG_BIG;
      if (kt * 64 + 63 > q0 + wv * 16) {   // diagonal tile for this wave
        #pragma unroll
        for (int mt = 0; mt < 4; ++mt) {
          #pragma unroll
          for (int r = 0; r < 4; ++r) {
            int key = kt * 64 + mt * 16 + quad * 4 + r;
            float v = sacc[mt][r];
            if (key > qrow) v = NEG_BIG;
            sacc[mt][r] = v;
            mx = fmaxf(mx, v);
          }
        }
      } else {
        #pragma unroll
        for (int mt = 0; mt < 4; ++mt) {
          #pragma unroll
          for (int r = 0; r < 4; ++r) mx = fmaxf(mx, sacc[mt][r]);
        }
      }
      mx = fmaxf(mx, __shfl_xor(mx, 16));
      mx = fmaxf(mx, __shfl_xor(mx, 32));

      // T13 defer-max: only rescale when the running max grew by >THR.
      if (__any(mx > m_q + RESCALE_THR)) {
        float mn = fmaxf(m_q, mx);
        float alpha = __builtin_exp2f(m_q - mn);
        m_q = mn;
        l_q *= alpha;
        #pragma unroll
        for (int mt8 = 0; mt8 < 8; ++mt8) {
          #pragma unroll
          for (int r = 0; r < 4; ++r) o[mt8][r] *= alpha;
        }
      }

      float rs = 0.f;
      #pragma unroll
      for (int mt = 0; mt < 4; ++mt) {
        #pragma unroll
        for (int r = 0; r < 4; ++r) {
          float pe = __builtin_exp2f(sacc[mt][r] - m_q);
          sacc[mt][r] = pe;
          rs += pe;
        }
      }
      rs += __shfl_xor(rs, 16);
      rs += __shfl_xor(rs, 32);
      l_q += rs;

      // P write (wave-private rows -> NO barrier): key = mt*16+quad*4+r
      // -> logical chunk 2*mt+(quad>>1), phys ^rsw, half (quad&1)*4.
      #pragma unroll
      for (int mt = 0; mt < 4; ++mt) {
        bf16x4 pk;
        #pragma unroll
        for (int r = 0; r < 4; ++r) pk[r] = (bf16_t)sacc[mt][r];
        int ch = 2 * mt + (quad >> 1);
        *(bf16x4*)(Pbase + (((ch ^ rsw) << 3) + (quad & 1) * 4)) = pk;
      }
      // P read: logical chunk 4*kh+quad, same involution, 16B-aligned.
      bf16x8 pf[2];
      #pragma unroll
      for (int kh = 0; kh < 2; ++kh)
        pf[kh] = *(const bf16x8*)(Pbase + (((4 * kh + quad) ^ rsw) << 3));

      __builtin_amdgcn_s_setprio(1);
      #pragma unroll
      for (int mt8 = 0; mt8 < 8; ++mt8) {
        int vrow = mt8 * 16 + c16;
        #pragma unroll
        for (int kh = 0; kh < 2; ++kh) {
          bf16x8 vf = *(const bf16x8*)(Vc + vrow * 64 +
                                       (((kh * 4 + quad) ^ (vrow & 7)) << 3));
          o[mt8] = __builtin_amdgcn_mfma_f32_16x16x32_bf16(vf, pf[kh], o[mt8], 0, 0, 0);
        }
      }
      __builtin_amdgcn_s_setprio(0);
    }
    cur ^= 1;
  }
  #undef STAGE

  // ---- normalize + coalesced store via O overlay ----
  __syncthreads();   // all K/VT/P reads done; pool reusable as O
  float inv = 1.0f / fmaxf(l_q, 1e-20f);
  bf16_t* Osh = sh;  // [128][136]
  #pragma unroll
  for (int mt8 = 0; mt8 < 8; ++mt8) {
    bf16x4 pk;
    #pragma unroll
    for (int r = 0; r < 4; ++r) pk[r] = (bf16_t)(o[mt8][r] * inv);
    *(bf16x4*)(&Osh[(size_t)prow * 136 + mt8 * 16 + quad * 4]) = pk;
  }
  // rows are wave-private; compiler inserts the lgkmcnt for the DS RAW
  int ql = lane >> 2, dc = lane & 3;
  #pragma unroll
  for (int i = 0; i < 4; ++i) {
    bf16x8 v = *(const bf16x8*)(&Osh[(size_t)(wv * 16 + ql) * 136 + dc * 8 + i * 32]);
    *(bf16x8*)(out + ((size_t)(b * S_LEN + q0 + wv * 16 + ql)) * HID
                   + h * HD + dc * 8 + i * 32) = v;
  }
}

extern "C" void kernel_launch(void* const* d_in, const int* in_sizes, int n_in,
                              void* d_out, int out_size, void* d_ws, size_t ws_size,
                              hipStream_t stream) {
  const float* hidden_f   = (const float*)d_in[0];
  // d_in[1] = attention_mask (deterministic causal) -- ignored
  const float* c_attn_w_f = (const float*)d_in[2];
  const float* c_attn_b_f = (const float*)d_in[3];
  const float* c_proj_w_f = (const float*)d_in[4];
  const float* c_proj_b_f = (const float*)d_in[5];
  float* out = (float*)d_out;

  const int M = 2 * S_LEN;                 // 4096
  const int nH  = M * HID;
  const int nWq = HID * QKVN;
  const int nWp = HID * HID;

  bf16_t* hbf   = (bf16_t*)d_ws;
  bf16_t* wqT   = hbf  + nH;               // WT_qkv [2304][2048]
  bf16_t* wpT   = wqT  + nWq;              // WT_proj[2048][2048]
  bf16_t* qkv   = wpT  + nWp;              // [4096][2304]
  bf16_t* attn  = qkv  + (size_t)M * QKVN; // [4096][2048]
  bf16_t* vtg   = attn + (size_t)M * HID;  // V^T [2][128][2048]

  cvt_f32_bf16_kernel<<<nH / 1024, 256, 0, stream>>>(hidden_f, hbf, nH);
  dim3 gt1(QKVN / 64, HID / 32);
  transpose_cvt_kernel<<<gt1, 256, 0, stream>>>(c_attn_w_f, wqT, HID, QKVN);
  dim3 gt2(HID / 64, HID / 32);
  transpose_cvt_kernel<<<gt2, 256, 0, stream>>>(c_proj_w_f, wpT, HID, HID);

  dim3 g1(QKVN / 128, M / 128);
  gemm_bias_kernel<bf16_t><<<g1, 256, 0, stream>>>(hbf, wqT, c_attn_b_f, qkv,
                                                   HID, HID, QKVN);

  dim3 gv(S_LEN / 16, 2);
  vt_extract_kernel<<<gv, 256, 0, stream>>>(qkv, vtg);

  dim3 g2(16, NH, 2);
  mqa_attn_kernel<<<g2, 512, 0, stream>>>(qkv, vtg, attn);

  dim3 g3(HID / 128, M / 128);
  gemm_bias_kernel<float><<<g3, 256, 0, stream>>>(attn, wpT, c_proj_b_f, out,
                                                  HID, HID, HID);
}

// Round 9
// 300.447 us; speedup vs baseline: 1.2825x; 1.0026x over previous
//
#include <hip/hip_runtime.h>
#include <hip/hip_bf16.h>

typedef __bf16 bf16_t;
typedef __bf16 bf16x8 __attribute__((ext_vector_type(8)));
typedef __bf16 bf16x4 __attribute__((ext_vector_type(4)));
typedef float f32x4 __attribute__((ext_vector_type(4)));

#define S_LEN 2048
#define HID   2048
#define NH    16
#define HD    128
#define QKVN  2304   // 2048 + 2*128
#define NEG_BIG (-30000.0f)
#define RESCALE_THR 8.0f

// direct global->LDS DMA, 16B per lane. lds dst must be the WAVE-UNIFORM base;
// HW adds lane*16 itself (m104). No LDS padding allowed in the covered range.
__device__ __forceinline__ void gld_lds16(const bf16_t* g, bf16_t* l) {
  __builtin_amdgcn_global_load_lds(
      (const __attribute__((address_space(1))) void*)((const void*)g),
      (__attribute__((address_space(3))) void*)((void*)l), 16, 0, 0);
}

// ---------------------------------------------------------------------------
// fp32 -> bf16 downcast, float4-vectorized.
// ---------------------------------------------------------------------------
__global__ __launch_bounds__(256) void cvt_f32_bf16_kernel(
    const float* __restrict__ in, bf16_t* __restrict__ out, int n)
{
  int i = (blockIdx.x * 256 + threadIdx.x) * 4;
  if (i < n) {
    float4 v = *(const float4*)(in + i);
    bf16x4 o;
    o[0] = (bf16_t)v.x; o[1] = (bf16_t)v.y; o[2] = (bf16_t)v.z; o[3] = (bf16_t)v.w;
    *(bf16x4*)(out + i) = o;
  }
}

// ---------------------------------------------------------------------------
// fp32 W[K][N] -> bf16 WT[N][K].
// ---------------------------------------------------------------------------
__global__ __launch_bounds__(256) void transpose_cvt_kernel(
    const float* __restrict__ in, bf16_t* __restrict__ out, int K, int N)
{
  int nc = threadIdx.x & 63;
  int kg = threadIdx.x >> 6;
  int n  = blockIdx.x * 64 + nc;
  int kb = blockIdx.y * 32 + kg * 8;
  bf16x8 v;
  #pragma unroll
  for (int i = 0; i < 8; ++i) v[i] = (bf16_t)in[(size_t)(kb + i) * N + n];
  *(bf16x8*)(out + (size_t)n * K + kb) = v;
}

// ---------------------------------------------------------------------------
// Extract V^T from qkv: vtg[b][d][s] = qkv[b*S+s][2176+d].
// ---------------------------------------------------------------------------
__global__ __launch_bounds__(256) void vt_extract_kernel(
    const bf16_t* __restrict__ qkv, bf16_t* __restrict__ vtg)
{
  int d  = threadIdx.x & 127;
  int sg = threadIdx.x >> 7;
  int b  = blockIdx.y;
  int s8 = blockIdx.x * 2 + sg;
  bf16x8 v;
  #pragma unroll
  for (int i = 0; i < 8; ++i)
    v[i] = qkv[((size_t)(b * S_LEN + s8 * 8 + i)) * QKVN + HID + HD + d];
  *(bf16x8*)(vtg + ((size_t)(b * HD + d)) * S_LEN + s8 * 8) = v;
}

// ---------------------------------------------------------------------------
// GEMM: C[M,N] = A[M,K] @ WT^T + bias (WT pre-transposed [N][K]).
// 128x128 C-tile, BK=64. T1 XCD swizzle (verified r5). 1-barrier
// double-buffered gld_lds schedule (verified r7 attn / r8 GEMM).
//
// Round-9: 8-WAVE blocks (512 thr). Round-8 post-mortem: double-buffering
// was a NULL on the GEMM (81.7->81.1 us, MfmaUtil 18.4->18.3) while the
// same schedule gained 35% on the 8-wave attention kernel. Diagnosis:
// 4-wave blocks at grid-capped 2 blocks/CU = 2 waves/SIMD — every per-wave
// stall (ds_read latency, MFMA dep chain, barrier converge) is a SIMD
// stall. Re-tile: 8 waves as 2x4, wave tile 64x32, acc[4][2]; grid + LDS
// unchanged -> 2 blocks/CU = 16 waves/CU = 4 waves/SIMD (the attention
// kernel's working point). LDS read traffic +50% (6 reads / 8 MFMA) but
// measured 0 conflicts at ~47 B/cyc vs ~112 ceiling — headroom exists.
// ---------------------------------------------------------------------------
template <typename OutT>
__global__ __launch_bounds__(512, 4) void gemm_bias_kernel(
    const bf16_t* __restrict__ A, const bf16_t* __restrict__ WT,
    const float* __restrict__ bias, OutT* __restrict__ C,
    int K, int lda, int ldc)
{
  __shared__ bf16_t Ash[2 * 128 * 64];   // [buf][m][k] swizzled, NO padding
  __shared__ bf16_t Bsh[2 * 128 * 64];   // [buf][n][k] swizzled, NO padding

  const int tid  = threadIdx.x;
  const int wave = tid >> 6;
  const int lane = tid & 63;
  const int quad = lane >> 4;
  const int c16  = lane & 15;
  const int wm = wave >> 2;          // 0..1 : 64-row half
  const int wn = wave & 3;           // 0..3 : 32-col quarter

  // T1 XCD swizzle: id -> (id%8)*cpx + id/8, bijective when nwg%8==0.
  int id  = (int)(blockIdx.y * gridDim.x + blockIdx.x);
  int nwg = (int)(gridDim.x * gridDim.y);
  int swz = (nwg & 7) ? id : ((id & 7) * (nwg >> 3) + (id >> 3));
  const int n0 = (swz % (int)gridDim.x) * 128;
  const int m0 = (swz / (int)gridDim.x) * 128;

  f32x4 acc[4][2] = {};

  // 1024 16B-chunks per operand tile; wave stages [wave*128, wave*128+128).
  // Slot c holds global chunk (row=c>>3, kc=(c^row)&7) — XOR chunk fetch,
  // matching the swizzled read below. LDS dst is the wave-uniform base.
  #define GSTAGE(bufi, k0v) do {                                             \
    bf16_t* Ad_ = Ash + (bufi) * 8192;                                       \
    bf16_t* Bd_ = Bsh + (bufi) * 8192;                                       \
    _Pragma("unroll")                                                        \
    for (int j_ = 0; j_ < 2; ++j_) {                                         \
      int cbase_ = wave * 128 + j_ * 64;                                     \
      int c_ = cbase_ + lane;                                                \
      int row_ = c_ >> 3;                                                    \
      int kcl_ = (c_ ^ row_) & 7;                                            \
      gld_lds16(A  + (size_t)(m0 + row_) * lda + (k0v) + kcl_ * 8,           \
                Ad_ + cbase_ * 8);                                           \
      gld_lds16(WT + (size_t)(n0 + row_) * K   + (k0v) + kcl_ * 8,           \
                Bd_ + cbase_ * 8);                                           \
    }                                                                        \
  } while (0)

  GSTAGE(0, 0);
  int cur = 0;

  for (int k0 = 0; k0 < K; k0 += 64) {
    // __syncthreads = s_waitcnt vmcnt(0) lgkmcnt(0) + s_barrier: completes
    // buf[cur]'s DMA (issued one K-step ago) AND rendezvous so the DMA
    // issued below may overwrite the buffer read last step.
    __syncthreads();
    if (k0 + 64 < K) GSTAGE(cur ^ 1, k0 + 64);

    const bf16_t* Ac = Ash + cur * 8192;
    const bf16_t* Bc = Bsh + cur * 8192;
    #pragma unroll
    for (int kk = 0; kk < 2; ++kk) {
      bf16x8 af[4], bfr[2];
      #pragma unroll
      for (int rb = 0; rb < 4; ++rb) {
        int row = wm * 64 + rb * 16 + c16;
        int kcp = ((kk * 4 + quad) ^ row) & 7;
        af[rb] = *(const bf16x8*)(Ac + row * 64 + kcp * 8);
      }
      #pragma unroll
      for (int nt = 0; nt < 2; ++nt) {
        int row = wn * 32 + nt * 16 + c16;
        int kcp = ((kk * 4 + quad) ^ row) & 7;
        bfr[nt] = *(const bf16x8*)(Bc + row * 64 + kcp * 8);
      }
      #pragma unroll
      for (int rb = 0; rb < 4; ++rb)
        #pragma unroll
        for (int nt = 0; nt < 2; ++nt)
          acc[rb][nt] = __builtin_amdgcn_mfma_f32_16x16x32_bf16(af[rb], bfr[nt],
                                                                acc[rb][nt], 0, 0, 0);
    }
    cur ^= 1;
  }
  #undef GSTAGE

  #pragma unroll
  for (int nt = 0; nt < 2; ++nt) {
    int col = n0 + wn * 32 + nt * 16 + c16;
    float bv = bias[col];
    #pragma unroll
    for (int rb = 0; rb < 4; ++rb) {
      int rbase = m0 + wm * 64 + rb * 16 + quad * 4;
      #pragma unroll
      for (int r = 0; r < 4; ++r)
        C[(size_t)(rbase + r) * ldc + col] = (OutT)(acc[rb][nt][r] + bv);
    }
  }
}

// ---------------------------------------------------------------------------
// Causal MQA attention, S^T formulation, QBLK=128, 8 waves.
// (verified round 7 — unchanged: single barrier per tile, double-buffered
// global_load_lds DMA staging, dedicated P region, T13 + T5, load-balance
// pairing. attn ~<=65 us, no longer the top dispatch.)
// ---------------------------------------------------------------------------
__global__ __launch_bounds__(512, 4) void mqa_attn_kernel(
    const bf16_t* __restrict__ qkv, const bf16_t* __restrict__ vtg,
    bf16_t* __restrict__ out)
{
  __shared__ bf16_t sh[40960];           // 81920 B
  // K[buf]  = sh + buf*8192           : [64][128]  keys x d   (swizzled)
  // VT[buf] = sh + 16384 + buf*8192   : [128][64]  d x keys   (swizzled)
  // P       = sh + 32768              : [128][64]  q x keys   (swizzled)
  // O overlay over sh[0..17408) after the loop.

  const int tid  = threadIdx.x;
  const int wv   = tid >> 6;             // 0..7 : q-strip
  const int lane = tid & 63;
  const int quad = lane >> 4;
  const int c16  = lane & 15;
  const int h = blockIdx.y;
  const int b = blockIdx.z;
  const float qscale = 0.08838834764831845f * 1.4426950408889634f; // /sqrt(128)*log2e

  const bf16_t* kbase = qkv + (size_t)b * S_LEN * QKVN + HID;
  const bf16_t* vtb   = vtg + (size_t)b * HD * S_LEN;

  const int qh = ((int)blockIdx.x + h) & 15;
  const int Q  = b ? (15 - qh) : qh;     // balanced pairing across batch axis
  const int q0 = Q * 128;
  const int qrow = q0 + wv * 16 + c16;
  const int ntile = 2 * Q + 2;           // 64-key tiles to process

  const bf16_t* qp = qkv + ((size_t)(b * S_LEN + qrow)) * QKVN + h * HD;
  bf16x8 qf[4];
  #pragma unroll
  for (int ks = 0; ks < 4; ++ks) {
    bf16x8 t = *(const bf16x8*)(qp + ks * 32 + quad * 8);
    #pragma unroll
    for (int j = 0; j < 8; ++j) t[j] = (bf16_t)((float)t[j] * qscale);
    qf[ks] = t;
  }

  float m_q = NEG_BIG, l_q = 0.0f;
  f32x4 o[8] = {};

  // P addressing (dedicated region, wave-private rows, XOR chunk swizzle)
  const int prow = wv * 16 + c16;
  const int rsw  = prow & 7;
  bf16_t* Pbase = sh + 32768 + (size_t)prow * 64;

  // DMA staging: K = 1024 chunks (64 rows x 16), VT = 1024 chunks (128 x 8).
  // Slot c holds source chunk (c&mask)^(row&7) of its row -> reads below
  // apply the same involution. LDS dst is the wave-uniform base (c & ~63).
  #define STAGE(bufi, kti) do {                                              \
    const bf16_t* kb_ = kbase + (size_t)(kti) * 64 * QKVN;                   \
    const bf16_t* vb_ = vtb + (kti) * 64;                                    \
    bf16_t* Kd_ = sh + (bufi) * 8192;                                        \
    bf16_t* Vd_ = sh + 16384 + (bufi) * 8192;                                \
    _Pragma("unroll")                                                        \
    for (int i_ = 0; i_ < 2; ++i_) {                                         \
      int c_ = tid + i_ * 512;                                               \
      int r_ = c_ >> 4, lc_ = (c_ & 15) ^ (r_ & 7);                          \
      gld_lds16(kb_ + (size_t)r_ * QKVN + lc_ * 8, Kd_ + (c_ & ~63) * 8);    \
    }                                                                        \
    _Pragma("unroll")                                                        \
    for (int i_ = 0; i_ < 2; ++i_) {                                         \
      int c_ = tid + i_ * 512;                                               \
      int r_ = c_ >> 3, lc_ = (c_ & 7) ^ (r_ & 7);                           \
      gld_lds16(vb_ + (size_t)r_ * S_LEN + lc_ * 8, Vd_ + (c_ & ~63) * 8);   \
    }                                                                        \
  } while (0)

  STAGE(0, 0);
  int cur = 0;

  for (int kt = 0; kt < ntile; ++kt) {
    // HIP __syncthreads = s_waitcnt vmcnt(0) lgkmcnt(0) + s_barrier:
    // completes buf[cur]'s DMA (issued one tile ago) AND rendezvous so the
    // DMA issued below may overwrite the buffer read last iteration.
    __syncthreads();
    if (kt + 1 < ntile) STAGE(cur ^ 1, kt + 1);

    const bf16_t* Kc = sh + cur * 8192;
    const bf16_t* Vc = sh + 16384 + cur * 8192;
    const bool wactive = (kt * 64) <= (q0 + wv * 16 + 15);
    if (wactive) {
      f32x4 sacc[4] = {};
      __builtin_amdgcn_s_setprio(1);
      #pragma unroll
      for (int mt = 0; mt < 4; ++mt) {
        int krow = mt * 16 + c16;
        #pragma unroll
        for (int ks = 0; ks < 4; ++ks) {
          bf16x8 kf = *(const bf16x8*)(Kc + krow * 128 +
                                       (((ks * 4 + quad) ^ (krow & 7)) << 3));
          sacc[mt] = __builtin_amdgcn_mfma_f32_16x16x32_bf16(kf, qf[ks], sacc[mt], 0, 0, 0);
        }
      }
      __builtin_amdgcn_s_setprio(0);

      float mx = NEG_BIG;
      if (kt * 64 + 63 > q0 + wv * 16) {   // diagonal tile for this wave
        #pragma unroll
        for (int mt = 0; mt < 4; ++mt) {
          #pragma unroll
          for (int r = 0; r < 4; ++r) {
            int key = kt * 64 + mt * 16 + quad * 4 + r;
            float v = sacc[mt][r];
            if (key > qrow) v = NEG_BIG;
            sacc[mt][r] = v;
            mx = fmaxf(mx, v);
          }
        }
      } else {
        #pragma unroll
        for (int mt = 0; mt < 4; ++mt) {
          #pragma unroll
          for (int r = 0; r < 4; ++r) mx = fmaxf(mx, sacc[mt][r]);
        }
      }
      mx = fmaxf(mx, __shfl_xor(mx, 16));
      mx = fmaxf(mx, __shfl_xor(mx, 32));

      // T13 defer-max: only rescale when the running max grew by >THR.
      if (__any(mx > m_q + RESCALE_THR)) {
        float mn = fmaxf(m_q, mx);
        float alpha = __builtin_exp2f(m_q - mn);
        m_q = mn;
        l_q *= alpha;
        #pragma unroll
        for (int mt8 = 0; mt8 < 8; ++mt8) {
          #pragma unroll
          for (int r = 0; r < 4; ++r) o[mt8][r] *= alpha;
        }
      }

      float rs = 0.f;
      #pragma unroll
      for (int mt = 0; mt < 4; ++mt) {
        #pragma unroll
        for (int r = 0; r < 4; ++r) {
          float pe = __builtin_exp2f(sacc[mt][r] - m_q);
          sacc[mt][r] = pe;
          rs += pe;
        }
      }
      rs += __shfl_xor(rs, 16);
      rs += __shfl_xor(rs, 32);
      l_q += rs;

      // P write (wave-private rows -> NO barrier): key = mt*16+quad*4+r
      // -> logical chunk 2*mt+(quad>>1), phys ^rsw, half (quad&1)*4.
      #pragma unroll
      for (int mt = 0; mt < 4; ++mt) {
        bf16x4 pk;
        #pragma unroll
        for (int r = 0; r < 4; ++r) pk[r] = (bf16_t)sacc[mt][r];
        int ch = 2 * mt + (quad >> 1);
        *(bf16x4*)(Pbase + (((ch ^ rsw) << 3) + (quad & 1) * 4)) = pk;
      }
      // P read: logical chunk 4*kh+quad, same involution, 16B-aligned.
      bf16x8 pf[2];
      #pragma unroll
      for (int kh = 0; kh < 2; ++kh)
        pf[kh] = *(const bf16x8*)(Pbase + (((4 * kh + quad) ^ rsw) << 3));

      __builtin_amdgcn_s_setprio(1);
      #pragma unroll
      for (int mt8 = 0; mt8 < 8; ++mt8) {
        int vrow = mt8 * 16 + c16;
        #pragma unroll
        for (int kh = 0; kh < 2; ++kh) {
          bf16x8 vf = *(const bf16x8*)(Vc + vrow * 64 +
                                       (((kh * 4 + quad) ^ (vrow & 7)) << 3));
          o[mt8] = __builtin_amdgcn_mfma_f32_16x16x32_bf16(vf, pf[kh], o[mt8], 0, 0, 0);
        }
      }
      __builtin_amdgcn_s_setprio(0);
    }
    cur ^= 1;
  }
  #undef STAGE

  // ---- normalize + coalesced store via O overlay ----
  __syncthreads();   // all K/VT/P reads done; pool reusable as O
  float inv = 1.0f / fmaxf(l_q, 1e-20f);
  bf16_t* Osh = sh;  // [128][136]
  #pragma unroll
  for (int mt8 = 0; mt8 < 8; ++mt8) {
    bf16x4 pk;
    #pragma unroll
    for (int r = 0; r < 4; ++r) pk[r] = (bf16_t)(o[mt8][r] * inv);
    *(bf16x4*)(&Osh[(size_t)prow * 136 + mt8 * 16 + quad * 4]) = pk;
  }
  // rows are wave-private; compiler inserts the lgkmcnt for the DS RAW
  int ql = lane >> 2, dc = lane & 3;
  #pragma unroll
  for (int i = 0; i < 4; ++i) {
    bf16x8 v = *(const bf16x8*)(&Osh[(size_t)(wv * 16 + ql) * 136 + dc * 8 + i * 32]);
    *(bf16x8*)(out + ((size_t)(b * S_LEN + q0 + wv * 16 + ql)) * HID
                   + h * HD + dc * 8 + i * 32) = v;
  }
}

extern "C" void kernel_launch(void* const* d_in, const int* in_sizes, int n_in,
                              void* d_out, int out_size, void* d_ws, size_t ws_size,
                              hipStream_t stream) {
  const float* hidden_f   = (const float*)d_in[0];
  // d_in[1] = attention_mask (deterministic causal) -- ignored
  const float* c_attn_w_f = (const float*)d_in[2];
  const float* c_attn_b_f = (const float*)d_in[3];
  const float* c_proj_w_f = (const float*)d_in[4];
  const float* c_proj_b_f = (const float*)d_in[5];
  float* out = (float*)d_out;

  const int M = 2 * S_LEN;                 // 4096
  const int nH  = M * HID;
  const int nWq = HID * QKVN;
  const int nWp = HID * HID;

  bf16_t* hbf   = (bf16_t*)d_ws;
  bf16_t* wqT   = hbf  + nH;               // WT_qkv [2304][2048]
  bf16_t* wpT   = wqT  + nWq;              // WT_proj[2048][2048]
  bf16_t* qkv   = wpT  + nWp;              // [4096][2304]
  bf16_t* attn  = qkv  + (size_t)M * QKVN; // [4096][2048]
  bf16_t* vtg   = attn + (size_t)M * HID;  // V^T [2][128][2048]

  cvt_f32_bf16_kernel<<<nH / 1024, 256, 0, stream>>>(hidden_f, hbf, nH);
  dim3 gt1(QKVN / 64, HID / 32);
  transpose_cvt_kernel<<<gt1, 256, 0, stream>>>(c_attn_w_f, wqT, HID, QKVN);
  dim3 gt2(HID / 64, HID / 32);
  transpose_cvt_kernel<<<gt2, 256, 0, stream>>>(c_proj_w_f, wpT, HID, HID);

  dim3 g1(QKVN / 128, M / 128);
  gemm_bias_kernel<bf16_t><<<g1, 512, 0, stream>>>(hbf, wqT, c_attn_b_f, qkv,
                                                   HID, HID, QKVN);

  dim3 gv(S_LEN / 16, 2);
  vt_extract_kernel<<<gv, 256, 0, stream>>>(qkv, vtg);

  dim3 g2(16, NH, 2);
  mqa_attn_kernel<<<g2, 512, 0, stream>>>(qkv, vtg, attn);

  dim3 g3(HID / 128, M / 128);
  gemm_bias_kernel<float><<<g3, 512, 0, stream>>>(attn, wpT, c_proj_b_f, out,
                                                  HID, HID, HID);
}

// Round 10
// 300.066 us; speedup vs baseline: 1.2842x; 1.0013x over previous
//
#include <hip/hip_runtime.h>
#include <hip/hip_bf16.h>

typedef __bf16 bf16_t;
typedef __bf16 bf16x8 __attribute__((ext_vector_type(8)));
typedef __bf16 bf16x4 __attribute__((ext_vector_type(4)));
typedef float f32x4 __attribute__((ext_vector_type(4)));

#define S_LEN 2048
#define HID   2048
#define NH    16
#define HD    128
#define QKVN  2304   // 2048 + 2*128
#define NEG_BIG (-30000.0f)
#define RESCALE_THR 8.0f

// direct global->LDS DMA, 16B per lane. lds dst must be the WAVE-UNIFORM base;
// HW adds lane*16 itself (m104). No LDS padding allowed in the covered range.
__device__ __forceinline__ void gld_lds16(const bf16_t* g, bf16_t* l) {
  __builtin_amdgcn_global_load_lds(
      (const __attribute__((address_space(1))) void*)((const void*)g),
      (__attribute__((address_space(3))) void*)((void*)l), 16, 0, 0);
}

// ---------------------------------------------------------------------------
// Fused prep: fp32->bf16 downcast of hidden states + both weight transposes.
// Round-10: was 3 separate dispatches (~16 us serial + 2 inter-dispatch
// gaps); the tasks are independent, so one flat grid runs them concurrently.
//   blocks [0, 8192)        : cvt hidden  (8M elems, 4/thread)
//   blocks [8192, 10496)    : W_qkv^T     (36 x 64 tiles)
//   blocks [10496, 12544)   : W_proj^T    (32 x 64 tiles)
// ---------------------------------------------------------------------------
__device__ __forceinline__ void transpose_cvt_body(
    const float* __restrict__ in, bf16_t* __restrict__ out,
    int K, int N, int bx, int by, int tid)
{
  int nc = tid & 63;
  int kg = tid >> 6;
  int n  = bx * 64 + nc;
  int kb = by * 32 + kg * 8;
  bf16x8 v;
  #pragma unroll
  for (int i = 0; i < 8; ++i) v[i] = (bf16_t)in[(size_t)(kb + i) * N + n];
  *(bf16x8*)(out + (size_t)n * K + kb) = v;
}

__global__ __launch_bounds__(256) void prep_kernel(
    const float* __restrict__ hidden, bf16_t* __restrict__ hbf,
    const float* __restrict__ wq, bf16_t* __restrict__ wqT,
    const float* __restrict__ wp, bf16_t* __restrict__ wpT)
{
  const int id  = blockIdx.x;
  const int tid = threadIdx.x;
  if (id < 8192) {
    int i = (id * 256 + tid) * 4;
    float4 v = *(const float4*)(hidden + i);
    bf16x4 o;
    o[0] = (bf16_t)v.x; o[1] = (bf16_t)v.y; o[2] = (bf16_t)v.z; o[3] = (bf16_t)v.w;
    *(bf16x4*)(hbf + i) = o;
  } else if (id < 8192 + 2304) {
    int id2 = id - 8192;
    transpose_cvt_body(wq, wqT, HID, QKVN, id2 % 36, id2 / 36, tid);
  } else {
    int id2 = id - 10496;
    transpose_cvt_body(wp, wpT, HID, HID, id2 % 32, id2 / 32, tid);
  }
}

// ---------------------------------------------------------------------------
// GEMM: C[M,N] = A[M,K] @ WT^T + bias (WT pre-transposed [N][K]).
// 128x128 C-tile, BK=64, 8 waves as 2x4 (wave 64x32, acc[4][2]) — verified
// round 9 (4 waves/SIMD; GEMMs dropped below attn). T1 XCD swizzle
// (verified r5). 1-barrier double-buffered gld_lds schedule (verified r7).
//
// Round-10: V^T extraction fused into the epilogue. The V columns of qkv
// are exactly the last 128-col tile (n0 == 2176, aligned): those 32 blocks
// additionally scatter their C values to vtg[b][d][s] (b=row>>11,
// s=row&2047). Bit-identical to the old vt_extract copy (same bf16 value).
// Saves one dispatch + its launch gap; scatter hidden under 544 other blocks.
// ---------------------------------------------------------------------------
template <typename OutT>
__global__ __launch_bounds__(512, 4) void gemm_bias_kernel(
    const bf16_t* __restrict__ A, const bf16_t* __restrict__ WT,
    const float* __restrict__ bias, OutT* __restrict__ C,
    bf16_t* __restrict__ vt_out, int K, int lda, int ldc)
{
  __shared__ bf16_t Ash[2 * 128 * 64];   // [buf][m][k] swizzled, NO padding
  __shared__ bf16_t Bsh[2 * 128 * 64];   // [buf][n][k] swizzled, NO padding

  const int tid  = threadIdx.x;
  const int wave = tid >> 6;
  const int lane = tid & 63;
  const int quad = lane >> 4;
  const int c16  = lane & 15;
  const int wm = wave >> 2;          // 0..1 : 64-row half
  const int wn = wave & 3;           // 0..3 : 32-col quarter

  // T1 XCD swizzle: id -> (id%8)*cpx + id/8, bijective when nwg%8==0.
  int id  = (int)(blockIdx.y * gridDim.x + blockIdx.x);
  int nwg = (int)(gridDim.x * gridDim.y);
  int swz = (nwg & 7) ? id : ((id & 7) * (nwg >> 3) + (id >> 3));
  const int n0 = (swz % (int)gridDim.x) * 128;
  const int m0 = (swz / (int)gridDim.x) * 128;

  f32x4 acc[4][2] = {};

  // 1024 16B-chunks per operand tile; wave stages [wave*128, wave*128+128).
  // Slot c holds global chunk (row=c>>3, kc=(c^row)&7) — XOR chunk fetch,
  // matching the swizzled read below. LDS dst is the wave-uniform base.
  #define GSTAGE(bufi, k0v) do {                                             \
    bf16_t* Ad_ = Ash + (bufi) * 8192;                                       \
    bf16_t* Bd_ = Bsh + (bufi) * 8192;                                       \
    _Pragma("unroll")                                                        \
    for (int j_ = 0; j_ < 2; ++j_) {                                         \
      int cbase_ = wave * 128 + j_ * 64;                                     \
      int c_ = cbase_ + lane;                                                \
      int row_ = c_ >> 3;                                                    \
      int kcl_ = (c_ ^ row_) & 7;                                            \
      gld_lds16(A  + (size_t)(m0 + row_) * lda + (k0v) + kcl_ * 8,           \
                Ad_ + cbase_ * 8);                                           \
      gld_lds16(WT + (size_t)(n0 + row_) * K   + (k0v) + kcl_ * 8,           \
                Bd_ + cbase_ * 8);                                           \
    }                                                                        \
  } while (0)

  GSTAGE(0, 0);
  int cur = 0;

  for (int k0 = 0; k0 < K; k0 += 64) {
    // __syncthreads = s_waitcnt vmcnt(0) lgkmcnt(0) + s_barrier: completes
    // buf[cur]'s DMA (issued one K-step ago) AND rendezvous so the DMA
    // issued below may overwrite the buffer read last step.
    __syncthreads();
    if (k0 + 64 < K) GSTAGE(cur ^ 1, k0 + 64);

    const bf16_t* Ac = Ash + cur * 8192;
    const bf16_t* Bc = Bsh + cur * 8192;
    #pragma unroll
    for (int kk = 0; kk < 2; ++kk) {
      bf16x8 af[4], bfr[2];
      #pragma unroll
      for (int rb = 0; rb < 4; ++rb) {
        int row = wm * 64 + rb * 16 + c16;
        int kcp = ((kk * 4 + quad) ^ row) & 7;
        af[rb] = *(const bf16x8*)(Ac + row * 64 + kcp * 8);
      }
      #pragma unroll
      for (int nt = 0; nt < 2; ++nt) {
        int row = wn * 32 + nt * 16 + c16;
        int kcp = ((kk * 4 + quad) ^ row) & 7;
        bfr[nt] = *(const bf16x8*)(Bc + row * 64 + kcp * 8);
      }
      #pragma unroll
      for (int rb = 0; rb < 4; ++rb)
        #pragma unroll
        for (int nt = 0; nt < 2; ++nt)
          acc[rb][nt] = __builtin_amdgcn_mfma_f32_16x16x32_bf16(af[rb], bfr[nt],
                                                                acc[rb][nt], 0, 0, 0);
    }
    cur ^= 1;
  }
  #undef GSTAGE

  const bool emit_vt = (vt_out != nullptr) && (n0 == HID + HD);
  #pragma unroll
  for (int nt = 0; nt < 2; ++nt) {
    int col = n0 + wn * 32 + nt * 16 + c16;
    float bv = bias[col];
    #pragma unroll
    for (int rb = 0; rb < 4; ++rb) {
      int rbase = m0 + wm * 64 + rb * 16 + quad * 4;
      #pragma unroll
      for (int r = 0; r < 4; ++r) {
        float val = acc[rb][nt][r] + bv;
        int row = rbase + r;
        C[(size_t)row * ldc + col] = (OutT)val;
        if (emit_vt) {
          int d = col - (HID + HD);
          vt_out[((size_t)(row >> 11) * HD + d) * S_LEN + (row & 2047)] =
              (bf16_t)val;
        }
      }
    }
  }
}

// ---------------------------------------------------------------------------
// Causal MQA attention, S^T formulation, QBLK=128, 8 waves.
// (verified round 7/9 — unchanged: single barrier per tile, double-buffered
// global_load_lds DMA staging, dedicated P region, T13 + T5, load-balance
// pairing. attn ~71.5 us, MfmaUtil 19.3.)
// ---------------------------------------------------------------------------
__global__ __launch_bounds__(512, 4) void mqa_attn_kernel(
    const bf16_t* __restrict__ qkv, const bf16_t* __restrict__ vtg,
    bf16_t* __restrict__ out)
{
  __shared__ bf16_t sh[40960];           // 81920 B
  // K[buf]  = sh + buf*8192           : [64][128]  keys x d   (swizzled)
  // VT[buf] = sh + 16384 + buf*8192   : [128][64]  d x keys   (swizzled)
  // P       = sh + 32768              : [128][64]  q x keys   (swizzled)
  // O overlay over sh[0..17408) after the loop.

  const int tid  = threadIdx.x;
  const int wv   = tid >> 6;             // 0..7 : q-strip
  const int lane = tid & 63;
  const int quad = lane >> 4;
  const int c16  = lane & 15;
  const int h = blockIdx.y;
  const int b = blockIdx.z;
  const float qscale = 0.08838834764831845f * 1.4426950408889634f; // /sqrt(128)*log2e

  const bf16_t* kbase = qkv + (size_t)b * S_LEN * QKVN + HID;
  const bf16_t* vtb   = vtg + (size_t)b * HD * S_LEN;

  const int qh = ((int)blockIdx.x + h) & 15;
  const int Q  = b ? (15 - qh) : qh;     // balanced pairing across batch axis
  const int q0 = Q * 128;
  const int qrow = q0 + wv * 16 + c16;
  const int ntile = 2 * Q + 2;           // 64-key tiles to process

  const bf16_t* qp = qkv + ((size_t)(b * S_LEN + qrow)) * QKVN + h * HD;
  bf16x8 qf[4];
  #pragma unroll
  for (int ks = 0; ks < 4; ++ks) {
    bf16x8 t = *(const bf16x8*)(qp + ks * 32 + quad * 8);
    #pragma unroll
    for (int j = 0; j < 8; ++j) t[j] = (bf16_t)((float)t[j] * qscale);
    qf[ks] = t;
  }

  float m_q = NEG_BIG, l_q = 0.0f;
  f32x4 o[8] = {};

  // P addressing (dedicated region, wave-private rows, XOR chunk swizzle)
  const int prow = wv * 16 + c16;
  const int rsw  = prow & 7;
  bf16_t* Pbase = sh + 32768 + (size_t)prow * 64;

  // DMA staging: K = 1024 chunks (64 rows x 16), VT = 1024 chunks (128 x 8).
  // Slot c holds source chunk (c&mask)^(row&7) of its row -> reads below
  // apply the same involution. LDS dst is the wave-uniform base (c & ~63).
  #define STAGE(bufi, kti) do {                                              \
    const bf16_t* kb_ = kbase + (size_t)(kti) * 64 * QKVN;                   \
    const bf16_t* vb_ = vtb + (kti) * 64;                                    \
    bf16_t* Kd_ = sh + (bufi) * 8192;                                        \
    bf16_t* Vd_ = sh + 16384 + (bufi) * 8192;                                \
    _Pragma("unroll")                                                        \
    for (int i_ = 0; i_ < 2; ++i_) {                                         \
      int c_ = tid + i_ * 512;                                               \
      int r_ = c_ >> 4, lc_ = (c_ & 15) ^ (r_ & 7);                          \
      gld_lds16(kb_ + (size_t)r_ * QKVN + lc_ * 8, Kd_ + (c_ & ~63) * 8);    \
    }                                                                        \
    _Pragma("unroll")                                                        \
    for (int i_ = 0; i_ < 2; ++i_) {                                         \
      int c_ = tid + i_ * 512;                                               \
      int r_ = c_ >> 3, lc_ = (c_ & 7) ^ (r_ & 7);                           \
      gld_lds16(vb_ + (size_t)r_ * S_LEN + lc_ * 8, Vd_ + (c_ & ~63) * 8);   \
    }                                                                        \
  } while (0)

  STAGE(0, 0);
  int cur = 0;

  for (int kt = 0; kt < ntile; ++kt) {
    // HIP __syncthreads = s_waitcnt vmcnt(0) lgkmcnt(0) + s_barrier:
    // completes buf[cur]'s DMA (issued one tile ago) AND rendezvous so the
    // DMA issued below may overwrite the buffer read last iteration.
    __syncthreads();
    if (kt + 1 < ntile) STAGE(cur ^ 1, kt + 1);

    const bf16_t* Kc = sh + cur * 8192;
    const bf16_t* Vc = sh + 16384 + cur * 8192;
    const bool wactive = (kt * 64) <= (q0 + wv * 16 + 15);
    if (wactive) {
      f32x4 sacc[4] = {};
      __builtin_amdgcn_s_setprio(1);
      #pragma unroll
      for (int mt = 0; mt < 4; ++mt) {
        int krow = mt * 16 + c16;
        #pragma unroll
        for (int ks = 0; ks < 4; ++ks) {
          bf16x8 kf = *(const bf16x8*)(Kc + krow * 128 +
                                       (((ks * 4 + quad) ^ (krow & 7)) << 3));
          sacc[mt] = __builtin_amdgcn_mfma_f32_16x16x32_bf16(kf, qf[ks], sacc[mt], 0, 0, 0);
        }
      }
      __builtin_amdgcn_s_setprio(0);

      float mx = NEG_BIG;
      if (kt * 64 + 63 > q0 + wv * 16) {   // diagonal tile for this wave
        #pragma unroll
        for (int mt = 0; mt < 4; ++mt) {
          #pragma unroll
          for (int r = 0; r < 4; ++r) {
            int key = kt * 64 + mt * 16 + quad * 4 + r;
            float v = sacc[mt][r];
            if (key > qrow) v = NEG_BIG;
            sacc[mt][r] = v;
            mx = fmaxf(mx, v);
          }
        }
      } else {
        #pragma unroll
        for (int mt = 0; mt < 4; ++mt) {
          #pragma unroll
          for (int r = 0; r < 4; ++r) mx = fmaxf(mx, sacc[mt][r]);
        }
      }
      mx = fmaxf(mx, __shfl_xor(mx, 16));
      mx = fmaxf(mx, __shfl_xor(mx, 32));

      // T13 defer-max: only rescale when the running max grew by >THR.
      if (__any(mx > m_q + RESCALE_THR)) {
        float mn = fmaxf(m_q, mx);
        float alpha = __builtin_exp2f(m_q - mn);
        m_q = mn;
        l_q *= alpha;
        #pragma unroll
        for (int mt8 = 0; mt8 < 8; ++mt8) {
          #pragma unroll
          for (int r = 0; r < 4; ++r) o[mt8][r] *= alpha;
        }
      }

      float rs = 0.f;
      #pragma unroll
      for (int mt = 0; mt < 4; ++mt) {
        #pragma unroll
        for (int r = 0; r < 4; ++r) {
          float pe = __builtin_exp2f(sacc[mt][r] - m_q);
          sacc[mt][r] = pe;
          rs += pe;
        }
      }
      rs += __shfl_xor(rs, 16);
      rs += __shfl_xor(rs, 32);
      l_q += rs;

      // P write (wave-private rows -> NO barrier): key = mt*16+quad*4+r
      // -> logical chunk 2*mt+(quad>>1), phys ^rsw, half (quad&1)*4.
      #pragma unroll
      for (int mt = 0; mt < 4; ++mt) {
        bf16x4 pk;
        #pragma unroll
        for (int r = 0; r < 4; ++r) pk[r] = (bf16_t)sacc[mt][r];
        int ch = 2 * mt + (quad >> 1);
        *(bf16x4*)(Pbase + (((ch ^ rsw) << 3) + (quad & 1) * 4)) = pk;
      }
      // P read: logical chunk 4*kh+quad, same involution, 16B-aligned.
      bf16x8 pf[2];
      #pragma unroll
      for (int kh = 0; kh < 2; ++kh)
        pf[kh] = *(const bf16x8*)(Pbase + (((4 * kh + quad) ^ rsw) << 3));

      __builtin_amdgcn_s_setprio(1);
      #pragma unroll
      for (int mt8 = 0; mt8 < 8; ++mt8) {
        int vrow = mt8 * 16 + c16;
        #pragma unroll
        for (int kh = 0; kh < 2; ++kh) {
          bf16x8 vf = *(const bf16x8*)(Vc + vrow * 64 +
                                       (((kh * 4 + quad) ^ (vrow & 7)) << 3));
          o[mt8] = __builtin_amdgcn_mfma_f32_16x16x32_bf16(vf, pf[kh], o[mt8], 0, 0, 0);
        }
      }
      __builtin_amdgcn_s_setprio(0);
    }
    cur ^= 1;
  }
  #undef STAGE

  // ---- normalize + coalesced store via O overlay ----
  __syncthreads();   // all K/VT/P reads done; pool reusable as O
  float inv = 1.0f / fmaxf(l_q, 1e-20f);
  bf16_t* Osh = sh;  // [128][136]
  #pragma unroll
  for (int mt8 = 0; mt8 < 8; ++mt8) {
    bf16x4 pk;
    #pragma unroll
    for (int r = 0; r < 4; ++r) pk[r] = (bf16_t)(o[mt8][r] * inv);
    *(bf16x4*)(&Osh[(size_t)prow * 136 + mt8 * 16 + quad * 4]) = pk;
  }
  // rows are wave-private; compiler inserts the lgkmcnt for the DS RAW
  int ql = lane >> 2, dc = lane & 3;
  #pragma unroll
  for (int i = 0; i < 4; ++i) {
    bf16x8 v = *(const bf16x8*)(&Osh[(size_t)(wv * 16 + ql) * 136 + dc * 8 + i * 32]);
    *(bf16x8*)(out + ((size_t)(b * S_LEN + q0 + wv * 16 + ql)) * HID
                   + h * HD + dc * 8 + i * 32) = v;
  }
}

extern "C" void kernel_launch(void* const* d_in, const int* in_sizes, int n_in,
                              void* d_out, int out_size, void* d_ws, size_t ws_size,
                              hipStream_t stream) {
  const float* hidden_f   = (const float*)d_in[0];
  // d_in[1] = attention_mask (deterministic causal) -- ignored
  const float* c_attn_w_f = (const float*)d_in[2];
  const float* c_attn_b_f = (const float*)d_in[3];
  const float* c_proj_w_f = (const float*)d_in[4];
  const float* c_proj_b_f = (const float*)d_in[5];
  float* out = (float*)d_out;

  const int M = 2 * S_LEN;                 // 4096
  const int nH  = M * HID;
  const int nWq = HID * QKVN;
  const int nWp = HID * HID;

  bf16_t* hbf   = (bf16_t*)d_ws;
  bf16_t* wqT   = hbf  + nH;               // WT_qkv [2304][2048]
  bf16_t* wpT   = wqT  + nWq;              // WT_proj[2048][2048]
  bf16_t* qkv   = wpT  + nWp;              // [4096][2304]
  bf16_t* attn  = qkv  + (size_t)M * QKVN; // [4096][2048]
  bf16_t* vtg   = attn + (size_t)M * HID;  // V^T [2][128][2048]

  // fused prep: cvt (8192 blocks) + W_qkv^T (2304) + W_proj^T (2048)
  prep_kernel<<<12544, 256, 0, stream>>>(hidden_f, hbf, c_attn_w_f, wqT,
                                         c_proj_w_f, wpT);

  dim3 g1(QKVN / 128, M / 128);
  gemm_bias_kernel<bf16_t><<<g1, 512, 0, stream>>>(hbf, wqT, c_attn_b_f, qkv,
                                                   vtg, HID, HID, QKVN);

  dim3 g2(16, NH, 2);
  mqa_attn_kernel<<<g2, 512, 0, stream>>>(qkv, vtg, attn);

  dim3 g3(HID / 128, M / 128);
  gemm_bias_kernel<float><<<g3, 512, 0, stream>>>(attn, wpT, c_proj_b_f, out,
                                                  (bf16_t*)nullptr, HID, HID, HID);
}